// Round 8
// baseline (313.864 us; speedup 1.0000x reference)
//
#include <hip/hip_runtime.h>
#include <hip/hip_bf16.h>
#include <hip/hip_cooperative_groups.h>
#include <cstdint>
#include <cstddef>

namespace cg = cooperative_groups;

#define NNODES 4096
#define NHEADS 4
#define NBR_STRIDE 128
#define NBLK 512

typedef __attribute__((ext_vector_type(8))) short bf16x8v;
typedef __attribute__((ext_vector_type(4))) float f32x4;

__device__ inline unsigned short bf16_rn(float f) {
    unsigned int u = __float_as_uint(f);
    u += 0x7FFFu + ((u >> 16) & 1u);
    return (unsigned short)(u >> 16);
}
__device__ inline float bf16_f32(unsigned short s) {
    return __uint_as_float(((unsigned int)s) << 16);
}

// ---------------------------------------------------------------------------
// build_nbr body: one wave per row (4 rows per call). All 16 float4 row-loads
// hoisted to registers before the serial ballot/compaction chain.
// ---------------------------------------------------------------------------
__device__ inline void build_nbr_body(
    const float* __restrict__ adj, int* __restrict__ nbr, int* __restrict__ deg,
    int rowblk) {
    int wave = threadIdx.x >> 6;
    int lane = threadIdx.x & 63;
    int row = rowblk * 4 + wave;
    const float4* arow = reinterpret_cast<const float4*>(adj + (size_t)row * NNODES);
    float4 v[16];
    #pragma unroll
    for (int it = 0; it < 16; ++it) v[it] = arow[it * 64 + lane];
    unsigned long long lt = (1ull << lane) - 1ull;
    int base = 0;
    #pragma unroll
    for (int it = 0; it < 16; ++it) {
        bool b0 = v[it].x > 0.f, b1 = v[it].y > 0.f, b2 = v[it].z > 0.f, b3 = v[it].w > 0.f;
        unsigned long long m0 = __ballot(b0);
        unsigned long long m1 = __ballot(b1);
        unsigned long long m2 = __ballot(b2);
        unsigned long long m3 = __ballot(b3);
        int pre = __popcll(m0 & lt) + __popcll(m1 & lt) +
                  __popcll(m2 & lt) + __popcll(m3 & lt);
        int pos = base + pre;
        int colb = it * 256 + lane * 4;
        if (b0) { if (pos < NBR_STRIDE) nbr[row * NBR_STRIDE + pos] = colb;     pos++; }
        if (b1) { if (pos < NBR_STRIDE) nbr[row * NBR_STRIDE + pos] = colb + 1; pos++; }
        if (b2) { if (pos < NBR_STRIDE) nbr[row * NBR_STRIDE + pos] = colb + 2; pos++; }
        if (b3) { if (pos < NBR_STRIDE) nbr[row * NBR_STRIDE + pos] = colb + 3; pos++; }
        base += __popcll(m0) + __popcll(m1) + __popcll(m2) + __popcll(m3);
    }
    if (lane == 0) deg[row] = base < NBR_STRIDE ? base : NBR_STRIDE;
}

// ---------------------------------------------------------------------------
// pack body: both layers' W -> transposed hi/lo bf16 (strided over grid)
// ---------------------------------------------------------------------------
__device__ inline void pack_body(
    const float* __restrict__ W1, const float* __restrict__ W2,
    unsigned short* __restrict__ B1h, unsigned short* __restrict__ B1l,
    unsigned short* __restrict__ B2h, unsigned short* __restrict__ B2l,
    int t) {
    if (t < 256 * 512) {
        int n = t >> 9, k = t & 511;
        int h = n >> 6, o = n & 63;
        float v = W1[((size_t)h * 512 + k) * 64 + o];
        unsigned short hi = bf16_rn(v);
        B1h[t] = hi;
        B1l[t] = bf16_rn(v - bf16_f32(hi));
    } else {
        int u = t - 256 * 512;
        if (u < 128 * 256) {
            int n = u >> 8, k = u & 255;
            int h = n >> 5, o = n & 31;
            float v = W2[((size_t)h * 256 + k) * 32 + o];
            unsigned short hi = bf16_rn(v);
            B2h[u] = hi;
            B2l[u] = bf16_rn(v - bf16_f32(hi));
        }
    }
}

// ---------------------------------------------------------------------------
// gemm body: C[M,N] = A[M,K](f32) * Bt[N,K]^T via hi*hi+hi*lo+lo*hi bf16 MFMA.
// Arena layout: Alh 0, All 4608, Blh 9216, Bll 18432, reds 27648, redd 27904.
// ---------------------------------------------------------------------------
template <int K, int N, int FO>
__device__ inline void gemm_body(
    char* arena,
    const float* __restrict__ A,
    const unsigned short* __restrict__ Bh, const unsigned short* __restrict__ Bl,
    const float* __restrict__ a, float* __restrict__ C,
    float* __restrict__ asrc, float* __restrict__ adst,
    int bx, int by) {
    constexpr int BM = 32, BN = 64, BK = 64, LP = BK + 8;
    typedef unsigned short (*lds_t)[LP];
    lds_t Alh = (lds_t)(arena);
    lds_t All = (lds_t)(arena + 4608);
    lds_t Blh = (lds_t)(arena + 9216);
    lds_t Bll = (lds_t)(arena + 18432);
    float* reds = (float*)(arena + 27648);   // [2][32]
    float* redd = (float*)(arena + 27904);   // [2][32]
    int tid = threadIdx.x;
    int wave = tid >> 6, lane = tid & 63;
    int rowBase = bx * BM;
    int colBase = by * BN;
    int wr = wave >> 1, wc = wave & 1;
    int lr = lane & 15, lk = lane >> 4;
    f32x4 acc0 = {0.f, 0.f, 0.f, 0.f};
    f32x4 acc1 = {0.f, 0.f, 0.f, 0.f};
    int ar = tid >> 3;            // 0..31
    int ac = (tid & 7) * 8;       // 8-elem chunks
    for (int k0 = 0; k0 < K; k0 += BK) {
        float4 a0 = *reinterpret_cast<const float4*>(&A[(size_t)(rowBase + ar) * K + k0 + ac]);
        float4 a1 = *reinterpret_cast<const float4*>(&A[(size_t)(rowBase + ar) * K + k0 + ac + 4]);
        uint4 bh0 = *reinterpret_cast<const uint4*>(&Bh[(size_t)(colBase + ar) * K + k0 + ac]);
        uint4 bl0 = *reinterpret_cast<const uint4*>(&Bl[(size_t)(colBase + ar) * K + k0 + ac]);
        uint4 bh1 = *reinterpret_cast<const uint4*>(&Bh[(size_t)(colBase + 32 + ar) * K + k0 + ac]);
        uint4 bl1 = *reinterpret_cast<const uint4*>(&Bl[(size_t)(colBase + 32 + ar) * K + k0 + ac]);
        __syncthreads();   // previous iteration's readers done
        ushort4 h4, l4;
        h4.x = bf16_rn(a0.x); l4.x = bf16_rn(a0.x - bf16_f32(h4.x));
        h4.y = bf16_rn(a0.y); l4.y = bf16_rn(a0.y - bf16_f32(h4.y));
        h4.z = bf16_rn(a0.z); l4.z = bf16_rn(a0.z - bf16_f32(h4.z));
        h4.w = bf16_rn(a0.w); l4.w = bf16_rn(a0.w - bf16_f32(h4.w));
        *reinterpret_cast<ushort4*>(&Alh[ar][ac]) = h4;
        *reinterpret_cast<ushort4*>(&All[ar][ac]) = l4;
        h4.x = bf16_rn(a1.x); l4.x = bf16_rn(a1.x - bf16_f32(h4.x));
        h4.y = bf16_rn(a1.y); l4.y = bf16_rn(a1.y - bf16_f32(h4.y));
        h4.z = bf16_rn(a1.z); l4.z = bf16_rn(a1.z - bf16_f32(h4.z));
        h4.w = bf16_rn(a1.w); l4.w = bf16_rn(a1.w - bf16_f32(h4.w));
        *reinterpret_cast<ushort4*>(&Alh[ar][ac + 4]) = h4;
        *reinterpret_cast<ushort4*>(&All[ar][ac + 4]) = l4;
        *reinterpret_cast<uint4*>(&Blh[ar][ac]) = bh0;
        *reinterpret_cast<uint4*>(&Bll[ar][ac]) = bl0;
        *reinterpret_cast<uint4*>(&Blh[32 + ar][ac]) = bh1;
        *reinterpret_cast<uint4*>(&Bll[32 + ar][ac]) = bl1;
        __syncthreads();
        #pragma unroll
        for (int ks = 0; ks < 2; ++ks) {
            int kb = ks * 32 + lk * 8;
            bf16x8v ah = *reinterpret_cast<const bf16x8v*>(&Alh[wr * 16 + lr][kb]);
            bf16x8v al = *reinterpret_cast<const bf16x8v*>(&All[wr * 16 + lr][kb]);
            bf16x8v b0h = *reinterpret_cast<const bf16x8v*>(&Blh[wc * 32 + lr][kb]);
            bf16x8v b0l = *reinterpret_cast<const bf16x8v*>(&Bll[wc * 32 + lr][kb]);
            bf16x8v b1h = *reinterpret_cast<const bf16x8v*>(&Blh[wc * 32 + 16 + lr][kb]);
            bf16x8v b1l = *reinterpret_cast<const bf16x8v*>(&Bll[wc * 32 + 16 + lr][kb]);
            acc0 = __builtin_amdgcn_mfma_f32_16x16x32_bf16(ah, b0h, acc0, 0, 0, 0);
            acc0 = __builtin_amdgcn_mfma_f32_16x16x32_bf16(ah, b0l, acc0, 0, 0, 0);
            acc0 = __builtin_amdgcn_mfma_f32_16x16x32_bf16(al, b0h, acc0, 0, 0, 0);
            acc1 = __builtin_amdgcn_mfma_f32_16x16x32_bf16(ah, b1h, acc1, 0, 0, 0);
            acc1 = __builtin_amdgcn_mfma_f32_16x16x32_bf16(ah, b1l, acc1, 0, 0, 0);
            acc1 = __builtin_amdgcn_mfma_f32_16x16x32_bf16(al, b1h, acc1, 0, 0, 0);
        }
    }
    // ---- write C ----
    int crow = rowBase + wr * 16 + lk * 4;
    int ccol = colBase + wc * 32 + lr;
    #pragma unroll
    for (int r = 0; r < 4; ++r) {
        C[(size_t)(crow + r) * N + ccol]      = acc0[r];
        C[(size_t)(crow + r) * N + ccol + 16] = acc1[r];
    }
    // ---- fused adot epilogue ----
    int n0 = colBase + wc * 32 + lr;
    int hh = n0 / FO;
    int o0 = n0 % FO;
    int o1 = o0 + 16;
    const float* av = a + hh * 2 * FO;
    float aS0 = av[o0], aS1 = av[o1];
    float aD0 = av[FO + o0], aD1 = av[FO + o1];
    float sv[4], dv[4];
    #pragma unroll
    for (int r = 0; r < 4; ++r) {
        sv[r] = acc0[r] * aS0 + acc1[r] * aS1;
        dv[r] = acc0[r] * aD0 + acc1[r] * aD1;
        #pragma unroll
        for (int msk = 1; msk < 16; msk <<= 1) {
            sv[r] += __shfl_xor(sv[r], msk);
            dv[r] += __shfl_xor(dv[r], msk);
        }
    }
    if constexpr (FO == 64) {
        if (lr == 0) {
            #pragma unroll
            for (int r = 0; r < 4; ++r) {
                reds[wc * 32 + wr * 16 + lk * 4 + r] = sv[r];
                redd[wc * 32 + wr * 16 + lk * 4 + r] = dv[r];
            }
        }
        __syncthreads();
        if (tid < BM) {
            int row = tid;
            asrc[by * NNODES + rowBase + row] = reds[row] + reds[32 + row];
            adst[by * NNODES + rowBase + row] = redd[row] + redd[32 + row];
        }
        __syncthreads();   // protect arena before reuse
    } else {
        if (lr == 0) {
            #pragma unroll
            for (int r = 0; r < 4; ++r) {
                asrc[hh * NNODES + rowBase + wr * 16 + lk * 4 + r] = sv[r];
                adst[hh * NNODES + rowBase + wr * 16 + lk * 4 + r] = dv[r];
            }
        }
    }
}

// ---------------------------------------------------------------------------
// agg body: sparse softmax + aggregation + ELU for node n; wave w = head w.
// Per-wave-private LDS slot (no block barrier). Gather loop unrolled x8.
// ---------------------------------------------------------------------------
template <int FO>
__device__ inline void agg_body(
    char* arena,
    const float* __restrict__ Wh,
    const float* __restrict__ asrc, const float* __restrict__ adst,
    const int* __restrict__ nbr, const int* __restrict__ deg,
    float* __restrict__ out, int n) {
    float2* sw = (float2*)arena;           // [4][NBR_STRIDE]
    int wslot = threadIdx.x >> 6;
    int lane = threadIdx.x & 63;
    int h = wslot;
    int dg = deg[n];
    const int* lst = nbr + n * NBR_STRIDE;
    float my_as = asrc[h * NNODES + n];

    int c0 = 0, c1 = 0;
    float e0 = -1e30f, e1 = -1e30f;
    if (lane < dg) {
        c0 = lst[lane];
        float e = my_as + adst[h * NNODES + c0];
        e0 = e >= 0.f ? e : 0.2f * e;
    }
    if (lane + 64 < dg) {
        c1 = lst[lane + 64];
        float e = my_as + adst[h * NNODES + c1];
        e1 = e >= 0.f ? e : 0.2f * e;
    }
    float m = fmaxf(e0, e1);
    #pragma unroll
    for (int s = 32; s; s >>= 1) m = fmaxf(m, __shfl_xor(m, s));
    float p0 = (lane < dg) ? __expf(e0 - m) : 0.f;
    float p1 = (lane + 64 < dg) ? __expf(e1 - m) : 0.f;
    float denom = p0 + p1;
    #pragma unroll
    for (int s = 32; s; s >>= 1) denom += __shfl_xor(denom, s);
    float inv = 1.0f / denom;

    if (lane < dg)      sw[wslot * NBR_STRIDE + lane]      = make_float2(p0 * inv, __int_as_float(c0));
    if (lane + 64 < dg) sw[wslot * NBR_STRIDE + lane + 64] = make_float2(p1 * inv, __int_as_float(c1));

    constexpr int STRIDE = NHEADS * FO;
    constexpr int LPR = FO / 4;      // lanes per neighbor row (16 or 8)
    constexpr int NPS = 64 / LPR;    // neighbors per step (4 or 8)
    int sub = lane / LPR;
    int dim4 = (lane % LPR) * 4;
    const float* whp = Wh + h * FO + dim4;
    f32x4 acc = {0.f, 0.f, 0.f, 0.f};
    int main_n = (dg / (8 * NPS)) * (8 * NPS);
    int k = 0;
    for (; k < main_n; k += 8 * NPS) {
        #pragma unroll
        for (int u = 0; u < 8; ++u) {
            float2 w = sw[wslot * NBR_STRIDE + k + u * NPS + sub];
            int col = __float_as_int(w.y);
            float4 v = *reinterpret_cast<const float4*>(&whp[(size_t)col * STRIDE]);
            acc[0] += w.x * v.x;
            acc[1] += w.x * v.y;
            acc[2] += w.x * v.z;
            acc[3] += w.x * v.w;
        }
    }
    for (; k < dg; k += NPS) {
        if (k + sub < dg) {
            float2 w = sw[wslot * NBR_STRIDE + k + sub];
            int col = __float_as_int(w.y);
            float4 v = *reinterpret_cast<const float4*>(&whp[(size_t)col * STRIDE]);
            acc[0] += w.x * v.x;
            acc[1] += w.x * v.y;
            acc[2] += w.x * v.z;
            acc[3] += w.x * v.w;
        }
    }
    #pragma unroll
    for (int s = LPR; s < 64; s <<= 1) {
        acc[0] += __shfl_xor(acc[0], s);
        acc[1] += __shfl_xor(acc[1], s);
        acc[2] += __shfl_xor(acc[2], s);
        acc[3] += __shfl_xor(acc[3], s);
    }
    if (lane < LPR) {
        float4 r;
        r.x = acc[0] > 0.f ? acc[0] : expm1f(acc[0]);
        r.y = acc[1] > 0.f ? acc[1] : expm1f(acc[1]);
        r.z = acc[2] > 0.f ? acc[2] : expm1f(acc[2]);
        r.w = acc[3] > 0.f ? acc[3] : expm1f(acc[3]);
        *reinterpret_cast<float4*>(&out[(size_t)n * STRIDE + h * FO + dim4]) = r;
    }
}

// ---------------------------------------------------------------------------
// Cooperative mega-kernel: 512 blocks x 256 threads (2 blocks/CU).
// ---------------------------------------------------------------------------
__global__ __launch_bounds__(256, 2) void mega_kernel(
    const float* __restrict__ adj, const float* __restrict__ x,
    const float* __restrict__ W1, const float* __restrict__ a1,
    const float* __restrict__ W2, const float* __restrict__ a2,
    int* __restrict__ nbr, int* __restrict__ deg,
    unsigned short* __restrict__ B1h, unsigned short* __restrict__ B1l,
    unsigned short* __restrict__ B2h, unsigned short* __restrict__ B2l,
    float* __restrict__ Wh1, float* __restrict__ as1, float* __restrict__ ad1,
    float* __restrict__ h1,
    float* __restrict__ Wh2, float* __restrict__ as2, float* __restrict__ ad2,
    float* __restrict__ out) {
    __shared__ __align__(16) char arena[28160];
    cg::grid_group grid = cg::this_grid();
    int b = blockIdx.x;

    // ---- Phase A: pack W hi/lo ----
    for (int t = b * 256 + (int)threadIdx.x; t < 256 * 512 + 128 * 256; t += NBLK * 256)
        pack_body(W1, W2, B1h, B1l, B2h, B2l, t);
    grid.sync();

    // ---- Phase B: gemm1 x2 (blocks 0..255) || build_nbr x4 (blocks 256..511) ----
    if (b < 256) {
        gemm_body<512, 256, 64>(arena, x, B1h, B1l, a1, Wh1, as1, ad1,
                                b & 127, b >> 7);
        gemm_body<512, 256, 64>(arena, x, B1h, B1l, a1, Wh1, as1, ad1,
                                (b + 256) & 127, (b + 256) >> 7);
    } else {
        int rb = (b - 256) * 4;
        #pragma unroll
        for (int j = 0; j < 4; ++j)
            build_nbr_body(adj, nbr, deg, rb + j);
    }
    grid.sync();

    // ---- Phase C: agg1 (8 nodes per block) ----
    #pragma unroll
    for (int q = 0; q < 8; ++q)
        agg_body<64>(arena, Wh1, as1, ad1, nbr, deg, h1, b * 8 + q);
    grid.sync();

    // ---- Phase D: gemm2 (blocks 0..255) ----
    if (b < 256) {
        gemm_body<256, 128, 32>(arena, h1, B2h, B2l, a2, Wh2, as2, ad2,
                                b & 127, b >> 7);
    }
    grid.sync();

    // ---- Phase E: agg2 (8 nodes per block) ----
    #pragma unroll
    for (int q = 0; q < 8; ++q)
        agg_body<32>(arena, Wh2, as2, ad2, nbr, deg, out, b * 8 + q);
}

// ---------------------------------------------------------------------------
// Fallback standalone kernels (round-6 proven path)
// ---------------------------------------------------------------------------
__global__ __launch_bounds__(256) void build_nbr_kernel(
    const float* __restrict__ adj, int* __restrict__ nbr, int* __restrict__ deg) {
    build_nbr_body(adj, nbr, deg, blockIdx.x);
}

__global__ __launch_bounds__(256) void pack_b_both_kernel(
    const float* __restrict__ W1, const float* __restrict__ W2,
    unsigned short* __restrict__ B1h, unsigned short* __restrict__ B1l,
    unsigned short* __restrict__ B2h, unsigned short* __restrict__ B2l) {
    pack_body(W1, W2, B1h, B1l, B2h, B2l, blockIdx.x * 256 + threadIdx.x);
}

template <int K, int N, int FO>
__global__ __launch_bounds__(256) void gemm_split_kernel(
    const float* __restrict__ A,
    const unsigned short* __restrict__ Bh, const unsigned short* __restrict__ Bl,
    const float* __restrict__ a, float* __restrict__ C,
    float* __restrict__ asrc, float* __restrict__ adst) {
    __shared__ __align__(16) char arena[28160];
    gemm_body<K, N, FO>(arena, A, Bh, Bl, a, C, asrc, adst, blockIdx.x, blockIdx.y);
}

template <int FO>
__global__ __launch_bounds__(256) void agg_kernel(
    const float* __restrict__ Wh,
    const float* __restrict__ asrc, const float* __restrict__ adst,
    const int* __restrict__ nbr, const int* __restrict__ deg,
    float* __restrict__ out) {
    __shared__ __align__(16) char arena[4096];
    agg_body<FO>(arena, Wh, asrc, adst, nbr, deg, out, blockIdx.x);
}

// ---------------------------------------------------------------------------
extern "C" void kernel_launch(void* const* d_in, const int* in_sizes, int n_in,
                              void* d_out, int out_size, void* d_ws, size_t ws_size,
                              hipStream_t stream) {
    const float* x   = (const float*)d_in[0];
    const float* adj = (const float*)d_in[1];
    const float* W1  = (const float*)d_in[2];
    const float* a1  = (const float*)d_in[3];
    const float* W2  = (const float*)d_in[4];
    const float* a2  = (const float*)d_in[5];
    float* outp = (float*)d_out;

    char* p = (char*)d_ws;
    auto alloc = [&](size_t bytes) -> void* {
        void* r = (void*)p;
        p += (bytes + 255) & ~(size_t)255;
        return r;
    };
    int*   nbr = (int*)alloc((size_t)NNODES * NBR_STRIDE * 4);
    int*   deg = (int*)alloc((size_t)NNODES * 4);
    unsigned short* B1h = (unsigned short*)alloc((size_t)256 * 512 * 2);
    unsigned short* B1l = (unsigned short*)alloc((size_t)256 * 512 * 2);
    unsigned short* B2h = (unsigned short*)alloc((size_t)128 * 256 * 2);
    unsigned short* B2l = (unsigned short*)alloc((size_t)128 * 256 * 2);
    float* Wh1 = (float*)alloc((size_t)NNODES * 256 * 4);
    float* as1 = (float*)alloc((size_t)NHEADS * NNODES * 4);
    float* ad1 = (float*)alloc((size_t)NHEADS * NNODES * 4);
    float* h1  = (float*)alloc((size_t)NNODES * 256 * 4);
    float* Wh2 = (float*)alloc((size_t)NNODES * 128 * 4);
    float* as2 = (float*)alloc((size_t)NHEADS * NNODES * 4);
    float* ad2 = (float*)alloc((size_t)NHEADS * NNODES * 4);

    // Deterministic co-residency check (host-side query; capture-safe).
    int blocksPerCU = 0;
    hipError_t qe = hipOccupancyMaxActiveBlocksPerMultiprocessor(
        &blocksPerCU, (const void*)mega_kernel, 256, 0);
    bool coop = (qe == hipSuccess) && (blocksPerCU * 256 >= NBLK);

    if (coop) {
        void* args[] = {
            (void*)&adj, (void*)&x, (void*)&W1, (void*)&a1, (void*)&W2, (void*)&a2,
            (void*)&nbr, (void*)&deg, (void*)&B1h, (void*)&B1l, (void*)&B2h, (void*)&B2l,
            (void*)&Wh1, (void*)&as1, (void*)&ad1, (void*)&h1,
            (void*)&Wh2, (void*)&as2, (void*)&ad2, (void*)&outp
        };
        hipError_t le = hipLaunchCooperativeKernel((const void*)mega_kernel,
                                                   dim3(NBLK), dim3(256),
                                                   args, 0, stream);
        if (le == hipSuccess) return;
        (void)hipGetLastError();   // clear and fall through to fallback
    }

    // ---- fallback: proven 6-kernel path ----
    pack_b_both_kernel<<<dim3((256 * 512 + 128 * 256) / 256), dim3(256), 0, stream>>>(
        W1, W2, B1h, B1l, B2h, B2l);
    build_nbr_kernel<<<dim3(NNODES / 4), dim3(256), 0, stream>>>(adj, nbr, deg);
    gemm_split_kernel<512, 256, 64><<<dim3(NNODES / 32, 4), dim3(256), 0, stream>>>(
        x, B1h, B1l, a1, Wh1, as1, ad1);
    agg_kernel<64><<<dim3(NNODES), dim3(256), 0, stream>>>(
        Wh1, as1, ad1, nbr, deg, h1);
    gemm_split_kernel<256, 128, 32><<<dim3(NNODES / 32, 2), dim3(256), 0, stream>>>(
        h1, B2h, B2l, a2, Wh2, as2, ad2);
    agg_kernel<32><<<dim3(NNODES), dim3(256), 0, stream>>>(
        Wh2, as2, ad2, nbr, deg, outp);
}

// Round 9
// 66.881 us; speedup vs baseline: 4.6928x; 4.6928x over previous
//
#include <hip/hip_runtime.h>
#include <hip/hip_bf16.h>
#include <cstdint>
#include <cstddef>

#define NNODES 4096
#define NHEADS 4
#define NBR_STRIDE 128

typedef __attribute__((ext_vector_type(8))) short bf16x8v;
typedef __attribute__((ext_vector_type(4))) float f32x4;

__device__ inline unsigned short bf16_rn(float f) {
    unsigned int u = __float_as_uint(f);
    u += 0x7FFFu + ((u >> 16) & 1u);
    return (unsigned short)(u >> 16);
}
__device__ inline float bf16_f32(unsigned short s) {
    return __uint_as_float(((unsigned int)s) << 16);
}

// ---------------------------------------------------------------------------
// build_nbr body: one wave per row (4 rows per call). All 16 float4 row-loads
// hoisted to registers before the serial ballot/compaction chain.
// ---------------------------------------------------------------------------
__device__ inline void build_nbr_body(
    const float* __restrict__ adj, int* __restrict__ nbr, int* __restrict__ deg,
    int rowblk) {
    int wave = threadIdx.x >> 6;
    int lane = threadIdx.x & 63;
    int row = rowblk * 4 + wave;
    const float4* arow = reinterpret_cast<const float4*>(adj + (size_t)row * NNODES);
    float4 v[16];
    #pragma unroll
    for (int it = 0; it < 16; ++it) v[it] = arow[it * 64 + lane];
    unsigned long long lt = (1ull << lane) - 1ull;
    int base = 0;
    #pragma unroll
    for (int it = 0; it < 16; ++it) {
        bool b0 = v[it].x > 0.f, b1 = v[it].y > 0.f, b2 = v[it].z > 0.f, b3 = v[it].w > 0.f;
        unsigned long long m0 = __ballot(b0);
        unsigned long long m1 = __ballot(b1);
        unsigned long long m2 = __ballot(b2);
        unsigned long long m3 = __ballot(b3);
        int pre = __popcll(m0 & lt) + __popcll(m1 & lt) +
                  __popcll(m2 & lt) + __popcll(m3 & lt);
        int pos = base + pre;
        int colb = it * 256 + lane * 4;
        if (b0) { if (pos < NBR_STRIDE) nbr[row * NBR_STRIDE + pos] = colb;     pos++; }
        if (b1) { if (pos < NBR_STRIDE) nbr[row * NBR_STRIDE + pos] = colb + 1; pos++; }
        if (b2) { if (pos < NBR_STRIDE) nbr[row * NBR_STRIDE + pos] = colb + 2; pos++; }
        if (b3) { if (pos < NBR_STRIDE) nbr[row * NBR_STRIDE + pos] = colb + 3; pos++; }
        base += __popcll(m0) + __popcll(m1) + __popcll(m2) + __popcll(m3);
    }
    if (lane == 0) deg[row] = base < NBR_STRIDE ? base : NBR_STRIDE;
}

// ---------------------------------------------------------------------------
// Kernel: pack BOTH layers' W -> transposed hi/lo bf16  Bt[N][K]
// ---------------------------------------------------------------------------
__global__ __launch_bounds__(256) void pack_b_both_kernel(
    const float* __restrict__ W1, const float* __restrict__ W2,
    unsigned short* __restrict__ B1h, unsigned short* __restrict__ B1l,
    unsigned short* __restrict__ B2h, unsigned short* __restrict__ B2l) {
    int t = blockIdx.x * 256 + threadIdx.x;
    if (t < 256 * 512) {
        int n = t >> 9, k = t & 511;
        int h = n >> 6, o = n & 63;
        float v = W1[((size_t)h * 512 + k) * 64 + o];
        unsigned short hi = bf16_rn(v);
        B1h[t] = hi;
        B1l[t] = bf16_rn(v - bf16_f32(hi));
    } else {
        int u = t - 256 * 512;
        if (u < 128 * 256) {
            int n = u >> 8, k = u & 255;
            int h = n >> 5, o = n & 31;
            float v = W2[((size_t)h * 256 + k) * 32 + o];
            unsigned short hi = bf16_rn(v);
            B2h[u] = hi;
            B2l[u] = bf16_rn(v - bf16_f32(hi));
        }
    }
}

// ---------------------------------------------------------------------------
// gemm body: C[M,N] = A[M,K](f32) * Bt[N,K]^T via hi*hi+hi*lo+lo*hi bf16 MFMA.
// A split to hi/lo in-kernel; B pre-packed (conflict-free uint4 LDS stores).
// BM=32, BN=64, BK=64; 4 waves, wave = 16 rows x 32 cols (2 frags).
// Epilogue: writes C + fused per-row attention dots.
// ---------------------------------------------------------------------------
template <int K, int N, int FO>
__device__ inline void gemm_body(
    char* arena,
    const float* __restrict__ A,
    const unsigned short* __restrict__ Bh, const unsigned short* __restrict__ Bl,
    const float* __restrict__ a, float* __restrict__ C,
    float* __restrict__ asrc, float* __restrict__ adst,
    int bx, int by) {
    constexpr int BM = 32, BN = 64, BK = 64, LP = BK + 8;
    typedef unsigned short (*lds_t)[LP];
    lds_t Alh = (lds_t)(arena);
    lds_t All = (lds_t)(arena + 4608);
    lds_t Blh = (lds_t)(arena + 9216);
    lds_t Bll = (lds_t)(arena + 18432);
    float* reds = (float*)(arena + 27648);   // [2][32]
    float* redd = (float*)(arena + 27904);   // [2][32]
    int tid = threadIdx.x;
    int wave = tid >> 6, lane = tid & 63;
    int rowBase = bx * BM;
    int colBase = by * BN;
    int wr = wave >> 1, wc = wave & 1;
    int lr = lane & 15, lk = lane >> 4;
    f32x4 acc0 = {0.f, 0.f, 0.f, 0.f};
    f32x4 acc1 = {0.f, 0.f, 0.f, 0.f};
    int ar = tid >> 3;            // 0..31
    int ac = (tid & 7) * 8;       // 8-elem chunks
    for (int k0 = 0; k0 < K; k0 += BK) {
        float4 a0 = *reinterpret_cast<const float4*>(&A[(size_t)(rowBase + ar) * K + k0 + ac]);
        float4 a1 = *reinterpret_cast<const float4*>(&A[(size_t)(rowBase + ar) * K + k0 + ac + 4]);
        uint4 bh0 = *reinterpret_cast<const uint4*>(&Bh[(size_t)(colBase + ar) * K + k0 + ac]);
        uint4 bl0 = *reinterpret_cast<const uint4*>(&Bl[(size_t)(colBase + ar) * K + k0 + ac]);
        uint4 bh1 = *reinterpret_cast<const uint4*>(&Bh[(size_t)(colBase + 32 + ar) * K + k0 + ac]);
        uint4 bl1 = *reinterpret_cast<const uint4*>(&Bl[(size_t)(colBase + 32 + ar) * K + k0 + ac]);
        __syncthreads();   // previous iteration's readers done
        ushort4 h4, l4;
        h4.x = bf16_rn(a0.x); l4.x = bf16_rn(a0.x - bf16_f32(h4.x));
        h4.y = bf16_rn(a0.y); l4.y = bf16_rn(a0.y - bf16_f32(h4.y));
        h4.z = bf16_rn(a0.z); l4.z = bf16_rn(a0.z - bf16_f32(h4.z));
        h4.w = bf16_rn(a0.w); l4.w = bf16_rn(a0.w - bf16_f32(h4.w));
        *reinterpret_cast<ushort4*>(&Alh[ar][ac]) = h4;
        *reinterpret_cast<ushort4*>(&All[ar][ac]) = l4;
        h4.x = bf16_rn(a1.x); l4.x = bf16_rn(a1.x - bf16_f32(h4.x));
        h4.y = bf16_rn(a1.y); l4.y = bf16_rn(a1.y - bf16_f32(h4.y));
        h4.z = bf16_rn(a1.z); l4.z = bf16_rn(a1.z - bf16_f32(h4.z));
        h4.w = bf16_rn(a1.w); l4.w = bf16_rn(a1.w - bf16_f32(h4.w));
        *reinterpret_cast<ushort4*>(&Alh[ar][ac + 4]) = h4;
        *reinterpret_cast<ushort4*>(&All[ar][ac + 4]) = l4;
        *reinterpret_cast<uint4*>(&Blh[ar][ac]) = bh0;
        *reinterpret_cast<uint4*>(&Bll[ar][ac]) = bl0;
        *reinterpret_cast<uint4*>(&Blh[32 + ar][ac]) = bh1;
        *reinterpret_cast<uint4*>(&Bll[32 + ar][ac]) = bl1;
        __syncthreads();
        #pragma unroll
        for (int ks = 0; ks < 2; ++ks) {
            int kb = ks * 32 + lk * 8;
            bf16x8v ah = *reinterpret_cast<const bf16x8v*>(&Alh[wr * 16 + lr][kb]);
            bf16x8v al = *reinterpret_cast<const bf16x8v*>(&All[wr * 16 + lr][kb]);
            bf16x8v b0h = *reinterpret_cast<const bf16x8v*>(&Blh[wc * 32 + lr][kb]);
            bf16x8v b0l = *reinterpret_cast<const bf16x8v*>(&Bll[wc * 32 + lr][kb]);
            bf16x8v b1h = *reinterpret_cast<const bf16x8v*>(&Blh[wc * 32 + 16 + lr][kb]);
            bf16x8v b1l = *reinterpret_cast<const bf16x8v*>(&Bll[wc * 32 + 16 + lr][kb]);
            acc0 = __builtin_amdgcn_mfma_f32_16x16x32_bf16(ah, b0h, acc0, 0, 0, 0);
            acc0 = __builtin_amdgcn_mfma_f32_16x16x32_bf16(ah, b0l, acc0, 0, 0, 0);
            acc0 = __builtin_amdgcn_mfma_f32_16x16x32_bf16(al, b0h, acc0, 0, 0, 0);
            acc1 = __builtin_amdgcn_mfma_f32_16x16x32_bf16(ah, b1h, acc1, 0, 0, 0);
            acc1 = __builtin_amdgcn_mfma_f32_16x16x32_bf16(ah, b1l, acc1, 0, 0, 0);
            acc1 = __builtin_amdgcn_mfma_f32_16x16x32_bf16(al, b1h, acc1, 0, 0, 0);
        }
    }
    // ---- write C ----
    int crow = rowBase + wr * 16 + lk * 4;
    int ccol = colBase + wc * 32 + lr;
    #pragma unroll
    for (int r = 0; r < 4; ++r) {
        C[(size_t)(crow + r) * N + ccol]      = acc0[r];
        C[(size_t)(crow + r) * N + ccol + 16] = acc1[r];
    }
    // ---- fused adot epilogue ----
    int n0 = colBase + wc * 32 + lr;
    int hh = n0 / FO;
    int o0 = n0 % FO;
    int o1 = o0 + 16;
    const float* av = a + hh * 2 * FO;
    float aS0 = av[o0], aS1 = av[o1];
    float aD0 = av[FO + o0], aD1 = av[FO + o1];
    float sv[4], dv[4];
    #pragma unroll
    for (int r = 0; r < 4; ++r) {
        sv[r] = acc0[r] * aS0 + acc1[r] * aS1;
        dv[r] = acc0[r] * aD0 + acc1[r] * aD1;
        #pragma unroll
        for (int msk = 1; msk < 16; msk <<= 1) {
            sv[r] += __shfl_xor(sv[r], msk);
            dv[r] += __shfl_xor(dv[r], msk);
        }
    }
    if constexpr (FO == 64) {
        if (lr == 0) {
            #pragma unroll
            for (int r = 0; r < 4; ++r) {
                reds[wc * 32 + wr * 16 + lk * 4 + r] = sv[r];
                redd[wc * 32 + wr * 16 + lk * 4 + r] = dv[r];
            }
        }
        __syncthreads();
        if (tid < BM) {
            int row = tid;
            asrc[by * NNODES + rowBase + row] = reds[row] + reds[32 + row];
            adst[by * NNODES + rowBase + row] = redd[row] + redd[32 + row];
        }
    } else {
        if (lr == 0) {
            #pragma unroll
            for (int r = 0; r < 4; ++r) {
                asrc[hh * NNODES + rowBase + wr * 16 + lk * 4 + r] = sv[r];
                adst[hh * NNODES + rowBase + wr * 16 + lk * 4 + r] = dv[r];
            }
        }
    }
}

// ---------------------------------------------------------------------------
// Fused kernel: blocks [0,512) = gemm1 tiles; [512,1536) = nbr (4 rows each).
// Pre-packed B -> conflict-free gemm; nbr blocks keep full-grid TLP.
// ---------------------------------------------------------------------------
__global__ __launch_bounds__(256) void fused1_kernel(
    const float* __restrict__ adj, int* __restrict__ nbr, int* __restrict__ deg,
    const float* __restrict__ x,
    const unsigned short* __restrict__ B1h, const unsigned short* __restrict__ B1l,
    const float* __restrict__ a1, float* __restrict__ Wh1,
    float* __restrict__ as1, float* __restrict__ ad1) {
    __shared__ __align__(16) char arena[28160];
    int b = blockIdx.x;
    if (b < 512) {
        gemm_body<512, 256, 64>(arena, x, B1h, B1l, a1, Wh1, as1, ad1,
                                b & 127, b >> 7);
    } else {
        build_nbr_body(adj, nbr, deg, b - 512);
    }
}

// ---------------------------------------------------------------------------
// Standalone gemm (layer 2)
// ---------------------------------------------------------------------------
template <int K, int N, int FO>
__global__ __launch_bounds__(256) void gemm_split_kernel(
    const float* __restrict__ A,
    const unsigned short* __restrict__ Bh, const unsigned short* __restrict__ Bl,
    const float* __restrict__ a, float* __restrict__ C,
    float* __restrict__ asrc, float* __restrict__ adst) {
    __shared__ __align__(16) char arena[28160];
    gemm_body<K, N, FO>(arena, A, Bh, Bl, a, C, asrc, adst, blockIdx.x, blockIdx.y);
}

// ---------------------------------------------------------------------------
// agg: sparse softmax + aggregation + ELU. One block per node; wave w = head w.
// float4 gathers, main loop unrolled x8.
// ---------------------------------------------------------------------------
template <int FO>
__global__ __launch_bounds__(256) void agg_kernel(
    const float* __restrict__ Wh,
    const float* __restrict__ asrc, const float* __restrict__ adst,
    const int* __restrict__ nbr, const int* __restrict__ deg,
    float* __restrict__ out) {
    __shared__ float2 sw[4][NBR_STRIDE];
    int wslot = threadIdx.x >> 6;
    int lane = threadIdx.x & 63;
    int n = blockIdx.x;
    int h = wslot;
    int dg = deg[n];
    const int* lst = nbr + n * NBR_STRIDE;
    float my_as = asrc[h * NNODES + n];

    int c0 = 0, c1 = 0;
    float e0 = -1e30f, e1 = -1e30f;
    if (lane < dg) {
        c0 = lst[lane];
        float e = my_as + adst[h * NNODES + c0];
        e0 = e >= 0.f ? e : 0.2f * e;
    }
    if (lane + 64 < dg) {
        c1 = lst[lane + 64];
        float e = my_as + adst[h * NNODES + c1];
        e1 = e >= 0.f ? e : 0.2f * e;
    }
    float m = fmaxf(e0, e1);
    #pragma unroll
    for (int s = 32; s; s >>= 1) m = fmaxf(m, __shfl_xor(m, s));
    float p0 = (lane < dg) ? __expf(e0 - m) : 0.f;
    float p1 = (lane + 64 < dg) ? __expf(e1 - m) : 0.f;
    float denom = p0 + p1;
    #pragma unroll
    for (int s = 32; s; s >>= 1) denom += __shfl_xor(denom, s);
    float inv = 1.0f / denom;

    if (lane < dg)      sw[wslot][lane]      = make_float2(p0 * inv, __int_as_float(c0));
    if (lane + 64 < dg) sw[wslot][lane + 64] = make_float2(p1 * inv, __int_as_float(c1));

    constexpr int STRIDE = NHEADS * FO;
    constexpr int LPR = FO / 4;      // lanes per neighbor row (16 or 8)
    constexpr int NPS = 64 / LPR;    // neighbors per step (4 or 8)
    int sub = lane / LPR;
    int dim4 = (lane % LPR) * 4;
    const float* whp = Wh + h * FO + dim4;
    f32x4 acc = {0.f, 0.f, 0.f, 0.f};
    int main_n = (dg / (8 * NPS)) * (8 * NPS);
    int k = 0;
    for (; k < main_n; k += 8 * NPS) {
        #pragma unroll
        for (int u = 0; u < 8; ++u) {
            float2 w = sw[wslot][k + u * NPS + sub];
            int col = __float_as_int(w.y);
            float4 v = *reinterpret_cast<const float4*>(&whp[(size_t)col * STRIDE]);
            acc[0] += w.x * v.x;
            acc[1] += w.x * v.y;
            acc[2] += w.x * v.z;
            acc[3] += w.x * v.w;
        }
    }
    for (; k < dg; k += NPS) {
        if (k + sub < dg) {
            float2 w = sw[wslot][k + sub];
            int col = __float_as_int(w.y);
            float4 v = *reinterpret_cast<const float4*>(&whp[(size_t)col * STRIDE]);
            acc[0] += w.x * v.x;
            acc[1] += w.x * v.y;
            acc[2] += w.x * v.z;
            acc[3] += w.x * v.w;
        }
    }
    #pragma unroll
    for (int s = LPR; s < 64; s <<= 1) {
        acc[0] += __shfl_xor(acc[0], s);
        acc[1] += __shfl_xor(acc[1], s);
        acc[2] += __shfl_xor(acc[2], s);
        acc[3] += __shfl_xor(acc[3], s);
    }
    if (lane < LPR) {
        float4 r;
        r.x = acc[0] > 0.f ? acc[0] : expm1f(acc[0]);
        r.y = acc[1] > 0.f ? acc[1] : expm1f(acc[1]);
        r.z = acc[2] > 0.f ? acc[2] : expm1f(acc[2]);
        r.w = acc[3] > 0.f ? acc[3] : expm1f(acc[3]);
        *reinterpret_cast<float4*>(&out[(size_t)n * STRIDE + h * FO + dim4]) = r;
    }
}

// ---------------------------------------------------------------------------
extern "C" void kernel_launch(void* const* d_in, const int* in_sizes, int n_in,
                              void* d_out, int out_size, void* d_ws, size_t ws_size,
                              hipStream_t stream) {
    const float* x   = (const float*)d_in[0];
    const float* adj = (const float*)d_in[1];
    const float* W1  = (const float*)d_in[2];
    const float* a1  = (const float*)d_in[3];
    const float* W2  = (const float*)d_in[4];
    const float* a2  = (const float*)d_in[5];
    float* outp = (float*)d_out;

    char* p = (char*)d_ws;
    auto alloc = [&](size_t bytes) -> void* {
        void* r = (void*)p;
        p += (bytes + 255) & ~(size_t)255;
        return r;
    };
    int*   nbr = (int*)alloc((size_t)NNODES * NBR_STRIDE * 4);
    int*   deg = (int*)alloc((size_t)NNODES * 4);
    unsigned short* B1h = (unsigned short*)alloc((size_t)256 * 512 * 2);
    unsigned short* B1l = (unsigned short*)alloc((size_t)256 * 512 * 2);
    unsigned short* B2h = (unsigned short*)alloc((size_t)128 * 256 * 2);
    unsigned short* B2l = (unsigned short*)alloc((size_t)128 * 256 * 2);
    float* Wh1 = (float*)alloc((size_t)NNODES * 256 * 4);
    float* as1 = (float*)alloc((size_t)NHEADS * NNODES * 4);
    float* ad1 = (float*)alloc((size_t)NHEADS * NNODES * 4);
    float* h1  = (float*)alloc((size_t)NNODES * 256 * 4);
    float* Wh2 = (float*)alloc((size_t)NNODES * 128 * 4);
    float* as2 = (float*)alloc((size_t)NHEADS * NNODES * 4);
    float* ad2 = (float*)alloc((size_t)NHEADS * NNODES * 4);

    // 1) pack W (tiny)
    pack_b_both_kernel<<<dim3((256 * 512 + 128 * 256) / 256), dim3(256), 0, stream>>>(
        W1, W2, B1h, B1l, B2h, B2l);
    // 2) fused: gemm1(+adot1) || build_nbr
    fused1_kernel<<<dim3(512 + NNODES / 4), dim3(256), 0, stream>>>(
        adj, nbr, deg, x, B1h, B1l, a1, Wh1, as1, ad1);
    // 3) agg1
    agg_kernel<64><<<dim3(NNODES), dim3(256), 0, stream>>>(
        Wh1, as1, ad1, nbr, deg, h1);
    // 4) gemm2(+adot2)
    gemm_split_kernel<256, 128, 32><<<dim3(NNODES / 32, 2), dim3(256), 0, stream>>>(
        h1, B2h, B2l, a2, Wh2, as2, ad2);
    // 5) agg2
    agg_kernel<32><<<dim3(NNODES), dim3(256), 0, stream>>>(
        Wh2, as2, ad2, nbr, deg, outp);
}

// Round 10
// 66.058 us; speedup vs baseline: 4.7514x; 1.0125x over previous
//
#include <hip/hip_runtime.h>
#include <hip/hip_bf16.h>
#include <cstdint>
#include <cstddef>

#define NNODES 4096
#define NHEADS 4
#define NBR_STRIDE 128

typedef __attribute__((ext_vector_type(8))) short bf16x8v;
typedef __attribute__((ext_vector_type(4))) float f32x4;

__device__ inline unsigned short bf16_rn(float f) {
    unsigned int u = __float_as_uint(f);
    u += 0x7FFFu + ((u >> 16) & 1u);
    return (unsigned short)(u >> 16);
}
__device__ inline float bf16_f32(unsigned short s) {
    return __uint_as_float(((unsigned int)s) << 16);
}

// ---------------------------------------------------------------------------
// build_nbr body: one wave per row (4 rows per block-call). All 16 float4
// row-loads hoisted to registers before the serial ballot/compaction chain.
// ---------------------------------------------------------------------------
__device__ inline void build_nbr_body(
    const float* __restrict__ adj, int* __restrict__ nbr, int* __restrict__ deg,
    int rowblk) {
    int wave = threadIdx.x >> 6;
    int lane = threadIdx.x & 63;
    int row = rowblk * 4 + wave;
    const float4* arow = reinterpret_cast<const float4*>(adj + (size_t)row * NNODES);
    float4 v[16];
    #pragma unroll
    for (int it = 0; it < 16; ++it) v[it] = arow[it * 64 + lane];
    unsigned long long lt = (1ull << lane) - 1ull;
    int base = 0;
    #pragma unroll
    for (int it = 0; it < 16; ++it) {
        bool b0 = v[it].x > 0.f, b1 = v[it].y > 0.f, b2 = v[it].z > 0.f, b3 = v[it].w > 0.f;
        unsigned long long m0 = __ballot(b0);
        unsigned long long m1 = __ballot(b1);
        unsigned long long m2 = __ballot(b2);
        unsigned long long m3 = __ballot(b3);
        int pre = __popcll(m0 & lt) + __popcll(m1 & lt) +
                  __popcll(m2 & lt) + __popcll(m3 & lt);
        int pos = base + pre;
        int colb = it * 256 + lane * 4;
        if (b0) { if (pos < NBR_STRIDE) nbr[row * NBR_STRIDE + pos] = colb;     pos++; }
        if (b1) { if (pos < NBR_STRIDE) nbr[row * NBR_STRIDE + pos] = colb + 1; pos++; }
        if (b2) { if (pos < NBR_STRIDE) nbr[row * NBR_STRIDE + pos] = colb + 2; pos++; }
        if (b3) { if (pos < NBR_STRIDE) nbr[row * NBR_STRIDE + pos] = colb + 3; pos++; }
        base += __popcll(m0) + __popcll(m1) + __popcll(m2) + __popcll(m3);
    }
    if (lane == 0) deg[row] = base < NBR_STRIDE ? base : NBR_STRIDE;
}

// ---------------------------------------------------------------------------
// Kernel: pack BOTH layers' W -> transposed hi/lo bf16  Bt[N][K]
// ---------------------------------------------------------------------------
__global__ __launch_bounds__(256) void pack_b_both_kernel(
    const float* __restrict__ W1, const float* __restrict__ W2,
    unsigned short* __restrict__ B1h, unsigned short* __restrict__ B1l,
    unsigned short* __restrict__ B2h, unsigned short* __restrict__ B2l) {
    int t = blockIdx.x * 256 + threadIdx.x;
    if (t < 256 * 512) {
        int n = t >> 9, k = t & 511;
        int h = n >> 6, o = n & 63;
        float v = W1[((size_t)h * 512 + k) * 64 + o];
        unsigned short hi = bf16_rn(v);
        B1h[t] = hi;
        B1l[t] = bf16_rn(v - bf16_f32(hi));
    } else {
        int u = t - 256 * 512;
        if (u < 128 * 256) {
            int n = u >> 8, k = u & 255;
            int h = n >> 5, o = n & 31;
            float v = W2[((size_t)h * 256 + k) * 32 + o];
            unsigned short hi = bf16_rn(v);
            B2h[u] = hi;
            B2l[u] = bf16_rn(v - bf16_f32(hi));
        }
    }
}

// ---------------------------------------------------------------------------
// gemm body: C[M,N] = A[M,K] * Bt[N,K]^T via hi*hi+hi*lo+lo*hi bf16 MFMA.
// A either f32 (split in-kernel; ASPLIT=false) or pre-split hi/lo bf16
// (ASPLIT=true). B pre-packed hi/lo. BM=32, BN=64; BK templated (32 or 64).
// 4 waves, wave = 16 rows x 32 cols (2 frags). Epilogue: C + fused adot.
// Arena bytes: 2*BM*LP*2 + 2*BN*LP*2 + 512  (BK=32 -> 15872, BK=64 -> 28160)
// ---------------------------------------------------------------------------
template <int K, int N, int FO, int BK, bool ASPLIT>
__device__ inline void gemm_body(
    char* arena,
    const float* __restrict__ A,
    const unsigned short* __restrict__ Ah, const unsigned short* __restrict__ Al,
    const unsigned short* __restrict__ Bh, const unsigned short* __restrict__ Bl,
    const float* __restrict__ a, float* __restrict__ C,
    float* __restrict__ asrc, float* __restrict__ adst,
    int bx, int by) {
    constexpr int BM = 32, BN = 64, LP = BK + 8;
    constexpr int ALD = BM * LP * 2;
    constexpr int BLD = BN * LP * 2;
    typedef unsigned short (*lds_t)[LP];
    lds_t Alh = (lds_t)(arena);
    lds_t All = (lds_t)(arena + ALD);
    lds_t Blh = (lds_t)(arena + 2 * ALD);
    lds_t Bll = (lds_t)(arena + 2 * ALD + BLD);
    float* reds = (float*)(arena + 2 * ALD + 2 * BLD);          // [2][32]
    float* redd = (float*)(arena + 2 * ALD + 2 * BLD + 256);    // [2][32]
    int tid = threadIdx.x;
    int wave = tid >> 6, lane = tid & 63;
    int rowBase = bx * BM;
    int colBase = by * BN;
    int wr = wave >> 1, wc = wave & 1;
    int lr = lane & 15, lk = lane >> 4;
    f32x4 acc0 = {0.f, 0.f, 0.f, 0.f};
    f32x4 acc1 = {0.f, 0.f, 0.f, 0.f};

    for (int k0 = 0; k0 < K; k0 += BK) {
        if constexpr (BK == 32) {
            int ar = tid >> 3, acf = (tid & 7) * 4;     // A: 32x32
            int br = tid >> 2, bc = (tid & 3) * 8;      // B: 64x32
            uint4 bh = *reinterpret_cast<const uint4*>(&Bh[(size_t)(colBase + br) * K + k0 + bc]);
            uint4 bl = *reinterpret_cast<const uint4*>(&Bl[(size_t)(colBase + br) * K + k0 + bc]);
            if constexpr (ASPLIT) {
                uint2 avh = *reinterpret_cast<const uint2*>(&Ah[(size_t)(rowBase + ar) * K + k0 + acf]);
                uint2 avl = *reinterpret_cast<const uint2*>(&Al[(size_t)(rowBase + ar) * K + k0 + acf]);
                __syncthreads();
                *reinterpret_cast<uint2*>(&Alh[ar][acf]) = avh;
                *reinterpret_cast<uint2*>(&All[ar][acf]) = avl;
                *reinterpret_cast<uint4*>(&Blh[br][bc]) = bh;
                *reinterpret_cast<uint4*>(&Bll[br][bc]) = bl;
            } else {
                float4 a0 = *reinterpret_cast<const float4*>(&A[(size_t)(rowBase + ar) * K + k0 + acf]);
                __syncthreads();
                ushort4 h4, l4;
                h4.x = bf16_rn(a0.x); l4.x = bf16_rn(a0.x - bf16_f32(h4.x));
                h4.y = bf16_rn(a0.y); l4.y = bf16_rn(a0.y - bf16_f32(h4.y));
                h4.z = bf16_rn(a0.z); l4.z = bf16_rn(a0.z - bf16_f32(h4.z));
                h4.w = bf16_rn(a0.w); l4.w = bf16_rn(a0.w - bf16_f32(h4.w));
                *reinterpret_cast<ushort4*>(&Alh[ar][acf]) = h4;
                *reinterpret_cast<ushort4*>(&All[ar][acf]) = l4;
                *reinterpret_cast<uint4*>(&Blh[br][bc]) = bh;
                *reinterpret_cast<uint4*>(&Bll[br][bc]) = bl;
            }
        } else {   // BK == 64
            int ar = tid >> 3, ac = (tid & 7) * 8;
            uint4 bh0 = *reinterpret_cast<const uint4*>(&Bh[(size_t)(colBase + ar) * K + k0 + ac]);
            uint4 bl0 = *reinterpret_cast<const uint4*>(&Bl[(size_t)(colBase + ar) * K + k0 + ac]);
            uint4 bh1 = *reinterpret_cast<const uint4*>(&Bh[(size_t)(colBase + 32 + ar) * K + k0 + ac]);
            uint4 bl1 = *reinterpret_cast<const uint4*>(&Bl[(size_t)(colBase + 32 + ar) * K + k0 + ac]);
            if constexpr (ASPLIT) {
                uint4 avh = *reinterpret_cast<const uint4*>(&Ah[(size_t)(rowBase + ar) * K + k0 + ac]);
                uint4 avl = *reinterpret_cast<const uint4*>(&Al[(size_t)(rowBase + ar) * K + k0 + ac]);
                __syncthreads();
                *reinterpret_cast<uint4*>(&Alh[ar][ac]) = avh;
                *reinterpret_cast<uint4*>(&All[ar][ac]) = avl;
                *reinterpret_cast<uint4*>(&Blh[ar][ac]) = bh0;
                *reinterpret_cast<uint4*>(&Bll[ar][ac]) = bl0;
                *reinterpret_cast<uint4*>(&Blh[32 + ar][ac]) = bh1;
                *reinterpret_cast<uint4*>(&Bll[32 + ar][ac]) = bl1;
            } else {
                float4 a0 = *reinterpret_cast<const float4*>(&A[(size_t)(rowBase + ar) * K + k0 + ac]);
                float4 a1 = *reinterpret_cast<const float4*>(&A[(size_t)(rowBase + ar) * K + k0 + ac + 4]);
                __syncthreads();
                ushort4 h4, l4;
                h4.x = bf16_rn(a0.x); l4.x = bf16_rn(a0.x - bf16_f32(h4.x));
                h4.y = bf16_rn(a0.y); l4.y = bf16_rn(a0.y - bf16_f32(h4.y));
                h4.z = bf16_rn(a0.z); l4.z = bf16_rn(a0.z - bf16_f32(h4.z));
                h4.w = bf16_rn(a0.w); l4.w = bf16_rn(a0.w - bf16_f32(h4.w));
                *reinterpret_cast<ushort4*>(&Alh[ar][ac]) = h4;
                *reinterpret_cast<ushort4*>(&All[ar][ac]) = l4;
                h4.x = bf16_rn(a1.x); l4.x = bf16_rn(a1.x - bf16_f32(h4.x));
                h4.y = bf16_rn(a1.y); l4.y = bf16_rn(a1.y - bf16_f32(h4.y));
                h4.z = bf16_rn(a1.z); l4.z = bf16_rn(a1.z - bf16_f32(h4.z));
                h4.w = bf16_rn(a1.w); l4.w = bf16_rn(a1.w - bf16_f32(h4.w));
                *reinterpret_cast<ushort4*>(&Alh[ar][ac + 4]) = h4;
                *reinterpret_cast<ushort4*>(&All[ar][ac + 4]) = l4;
                *reinterpret_cast<uint4*>(&Blh[ar][ac]) = bh0;
                *reinterpret_cast<uint4*>(&Bll[ar][ac]) = bl0;
                *reinterpret_cast<uint4*>(&Blh[32 + ar][ac]) = bh1;
                *reinterpret_cast<uint4*>(&Bll[32 + ar][ac]) = bl1;
            }
        }
        __syncthreads();
        #pragma unroll
        for (int ks = 0; ks < BK / 32; ++ks) {
            int kb = ks * 32 + lk * 8;
            bf16x8v ah = *reinterpret_cast<const bf16x8v*>(&Alh[wr * 16 + lr][kb]);
            bf16x8v al = *reinterpret_cast<const bf16x8v*>(&All[wr * 16 + lr][kb]);
            bf16x8v b0h = *reinterpret_cast<const bf16x8v*>(&Blh[wc * 32 + lr][kb]);
            bf16x8v b0l = *reinterpret_cast<const bf16x8v*>(&Bll[wc * 32 + lr][kb]);
            bf16x8v b1h = *reinterpret_cast<const bf16x8v*>(&Blh[wc * 32 + 16 + lr][kb]);
            bf16x8v b1l = *reinterpret_cast<const bf16x8v*>(&Bll[wc * 32 + 16 + lr][kb]);
            acc0 = __builtin_amdgcn_mfma_f32_16x16x32_bf16(ah, b0h, acc0, 0, 0, 0);
            acc0 = __builtin_amdgcn_mfma_f32_16x16x32_bf16(ah, b0l, acc0, 0, 0, 0);
            acc0 = __builtin_amdgcn_mfma_f32_16x16x32_bf16(al, b0h, acc0, 0, 0, 0);
            acc1 = __builtin_amdgcn_mfma_f32_16x16x32_bf16(ah, b1h, acc1, 0, 0, 0);
            acc1 = __builtin_amdgcn_mfma_f32_16x16x32_bf16(ah, b1l, acc1, 0, 0, 0);
            acc1 = __builtin_amdgcn_mfma_f32_16x16x32_bf16(al, b1h, acc1, 0, 0, 0);
        }
    }
    // ---- write C ----
    int crow = rowBase + wr * 16 + lk * 4;
    int ccol = colBase + wc * 32 + lr;
    #pragma unroll
    for (int r = 0; r < 4; ++r) {
        C[(size_t)(crow + r) * N + ccol]      = acc0[r];
        C[(size_t)(crow + r) * N + ccol + 16] = acc1[r];
    }
    // ---- fused adot epilogue ----
    int n0 = colBase + wc * 32 + lr;
    int hh = n0 / FO;
    int o0 = n0 % FO;
    int o1 = o0 + 16;
    const float* av = a + hh * 2 * FO;
    float aS0 = av[o0], aS1 = av[o1];
    float aD0 = av[FO + o0], aD1 = av[FO + o1];
    float sv[4], dv[4];
    #pragma unroll
    for (int r = 0; r < 4; ++r) {
        sv[r] = acc0[r] * aS0 + acc1[r] * aS1;
        dv[r] = acc0[r] * aD0 + acc1[r] * aD1;
        #pragma unroll
        for (int msk = 1; msk < 16; msk <<= 1) {
            sv[r] += __shfl_xor(sv[r], msk);
            dv[r] += __shfl_xor(dv[r], msk);
        }
    }
    if constexpr (FO == 64) {
        if (lr == 0) {
            #pragma unroll
            for (int r = 0; r < 4; ++r) {
                reds[wc * 32 + wr * 16 + lk * 4 + r] = sv[r];
                redd[wc * 32 + wr * 16 + lk * 4 + r] = dv[r];
            }
        }
        __syncthreads();
        if (tid < BM) {
            int row = tid;
            asrc[by * NNODES + rowBase + row] = reds[row] + reds[32 + row];
            adst[by * NNODES + rowBase + row] = redd[row] + redd[32 + row];
        }
    } else {
        if (lr == 0) {
            #pragma unroll
            for (int r = 0; r < 4; ++r) {
                asrc[hh * NNODES + rowBase + wr * 16 + lk * 4 + r] = sv[r];
                adst[hh * NNODES + rowBase + wr * 16 + lk * 4 + r] = dv[r];
            }
        }
    }
}

// ---------------------------------------------------------------------------
// Fused kernel: blocks [0,512) = gemm1 tiles (BK=32 -> 15.9KB LDS);
// [512,1536) = nbr (4 rows each). 15.9KB arena keeps nbr at 8 blocks/CU.
// ---------------------------------------------------------------------------
__global__ __launch_bounds__(256) void fused1_kernel(
    const float* __restrict__ adj, int* __restrict__ nbr, int* __restrict__ deg,
    const float* __restrict__ x,
    const unsigned short* __restrict__ B1h, const unsigned short* __restrict__ B1l,
    const float* __restrict__ a1, float* __restrict__ Wh1,
    float* __restrict__ as1, float* __restrict__ ad1) {
    __shared__ __align__(16) char arena[15872];
    int b = blockIdx.x;
    if (b < 512) {
        gemm_body<512, 256, 64, 32, false>(arena, x, nullptr, nullptr,
                                           B1h, B1l, a1, Wh1, as1, ad1,
                                           b & 127, b >> 7);
    } else {
        build_nbr_body(adj, nbr, deg, b - 512);
    }
}

// ---------------------------------------------------------------------------
// Standalone gemm (layer 2): pre-split A (h1h/h1l), BK=64.
// ---------------------------------------------------------------------------
__global__ __launch_bounds__(256) void gemm2_kernel(
    const unsigned short* __restrict__ Ah, const unsigned short* __restrict__ Al,
    const unsigned short* __restrict__ Bh, const unsigned short* __restrict__ Bl,
    const float* __restrict__ a, float* __restrict__ C,
    float* __restrict__ asrc, float* __restrict__ adst) {
    __shared__ __align__(16) char arena[28160];
    gemm_body<256, 128, 32, 64, true>(arena, nullptr, Ah, Al, Bh, Bl,
                                      a, C, asrc, adst, blockIdx.x, blockIdx.y);
}

// ---------------------------------------------------------------------------
// agg: sparse softmax + aggregation + ELU. One block per node; wave w = head w.
// float4 gathers, main loop unrolled x8. SPLITOUT: write hi/lo bf16 pair
// (pre-split for gemm2's A path) instead of f32.
// ---------------------------------------------------------------------------
template <int FO, bool SPLITOUT>
__global__ __launch_bounds__(256) void agg_kernel(
    const float* __restrict__ Wh,
    const float* __restrict__ asrc, const float* __restrict__ adst,
    const int* __restrict__ nbr, const int* __restrict__ deg,
    float* __restrict__ out,
    unsigned short* __restrict__ outh, unsigned short* __restrict__ outl) {
    __shared__ float2 sw[4][NBR_STRIDE];
    int wslot = threadIdx.x >> 6;
    int lane = threadIdx.x & 63;
    int n = blockIdx.x;
    int h = wslot;
    int dg = deg[n];
    const int* lst = nbr + n * NBR_STRIDE;
    float my_as = asrc[h * NNODES + n];

    int c0 = 0, c1 = 0;
    float e0 = -1e30f, e1 = -1e30f;
    if (lane < dg) {
        c0 = lst[lane];
        float e = my_as + adst[h * NNODES + c0];
        e0 = e >= 0.f ? e : 0.2f * e;
    }
    if (lane + 64 < dg) {
        c1 = lst[lane + 64];
        float e = my_as + adst[h * NNODES + c1];
        e1 = e >= 0.f ? e : 0.2f * e;
    }
    float m = fmaxf(e0, e1);
    #pragma unroll
    for (int s = 32; s; s >>= 1) m = fmaxf(m, __shfl_xor(m, s));
    float p0 = (lane < dg) ? __expf(e0 - m) : 0.f;
    float p1 = (lane + 64 < dg) ? __expf(e1 - m) : 0.f;
    float denom = p0 + p1;
    #pragma unroll
    for (int s = 32; s; s >>= 1) denom += __shfl_xor(denom, s);
    float inv = 1.0f / denom;

    if (lane < dg)      sw[wslot][lane]      = make_float2(p0 * inv, __int_as_float(c0));
    if (lane + 64 < dg) sw[wslot][lane + 64] = make_float2(p1 * inv, __int_as_float(c1));

    constexpr int STRIDE = NHEADS * FO;
    constexpr int LPR = FO / 4;      // lanes per neighbor row (16 or 8)
    constexpr int NPS = 64 / LPR;    // neighbors per step (4 or 8)
    int sub = lane / LPR;
    int dim4 = (lane % LPR) * 4;
    const float* whp = Wh + h * FO + dim4;
    f32x4 acc = {0.f, 0.f, 0.f, 0.f};
    int main_n = (dg / (8 * NPS)) * (8 * NPS);
    int k = 0;
    for (; k < main_n; k += 8 * NPS) {
        #pragma unroll
        for (int u = 0; u < 8; ++u) {
            float2 w = sw[wslot][k + u * NPS + sub];
            int col = __float_as_int(w.y);
            float4 v = *reinterpret_cast<const float4*>(&whp[(size_t)col * STRIDE]);
            acc[0] += w.x * v.x;
            acc[1] += w.x * v.y;
            acc[2] += w.x * v.z;
            acc[3] += w.x * v.w;
        }
    }
    for (; k < dg; k += NPS) {
        if (k + sub < dg) {
            float2 w = sw[wslot][k + sub];
            int col = __float_as_int(w.y);
            float4 v = *reinterpret_cast<const float4*>(&whp[(size_t)col * STRIDE]);
            acc[0] += w.x * v.x;
            acc[1] += w.x * v.y;
            acc[2] += w.x * v.z;
            acc[3] += w.x * v.w;
        }
    }
    #pragma unroll
    for (int s = LPR; s < 64; s <<= 1) {
        acc[0] += __shfl_xor(acc[0], s);
        acc[1] += __shfl_xor(acc[1], s);
        acc[2] += __shfl_xor(acc[2], s);
        acc[3] += __shfl_xor(acc[3], s);
    }
    if (lane < LPR) {
        float r0 = acc[0] > 0.f ? acc[0] : expm1f(acc[0]);
        float r1 = acc[1] > 0.f ? acc[1] : expm1f(acc[1]);
        float r2 = acc[2] > 0.f ? acc[2] : expm1f(acc[2]);
        float r3 = acc[3] > 0.f ? acc[3] : expm1f(acc[3]);
        size_t idx = (size_t)n * STRIDE + h * FO + dim4;
        if constexpr (SPLITOUT) {
            ushort4 hv, lv;
            hv.x = bf16_rn(r0); lv.x = bf16_rn(r0 - bf16_f32(hv.x));
            hv.y = bf16_rn(r1); lv.y = bf16_rn(r1 - bf16_f32(hv.y));
            hv.z = bf16_rn(r2); lv.z = bf16_rn(r2 - bf16_f32(hv.z));
            hv.w = bf16_rn(r3); lv.w = bf16_rn(r3 - bf16_f32(hv.w));
            *reinterpret_cast<ushort4*>(&outh[idx]) = hv;
            *reinterpret_cast<ushort4*>(&outl[idx]) = lv;
        } else {
            *reinterpret_cast<float4*>(&out[idx]) = make_float4(r0, r1, r2, r3);
        }
    }
}

// ---------------------------------------------------------------------------
extern "C" void kernel_launch(void* const* d_in, const int* in_sizes, int n_in,
                              void* d_out, int out_size, void* d_ws, size_t ws_size,
                              hipStream_t stream) {
    const float* x   = (const float*)d_in[0];
    const float* adj = (const float*)d_in[1];
    const float* W1  = (const float*)d_in[2];
    const float* a1  = (const float*)d_in[3];
    const float* W2  = (const float*)d_in[4];
    const float* a2  = (const float*)d_in[5];
    float* outp = (float*)d_out;

    char* p = (char*)d_ws;
    auto alloc = [&](size_t bytes) -> void* {
        void* r = (void*)p;
        p += (bytes + 255) & ~(size_t)255;
        return r;
    };
    int*   nbr = (int*)alloc((size_t)NNODES * NBR_STRIDE * 4);
    int*   deg = (int*)alloc((size_t)NNODES * 4);
    unsigned short* B1h = (unsigned short*)alloc((size_t)256 * 512 * 2);
    unsigned short* B1l = (unsigned short*)alloc((size_t)256 * 512 * 2);
    unsigned short* B2h = (unsigned short*)alloc((size_t)128 * 256 * 2);
    unsigned short* B2l = (unsigned short*)alloc((size_t)128 * 256 * 2);
    float* Wh1 = (float*)alloc((size_t)NNODES * 256 * 4);
    float* as1 = (float*)alloc((size_t)NHEADS * NNODES * 4);
    float* ad1 = (float*)alloc((size_t)NHEADS * NNODES * 4);
    unsigned short* h1h = (unsigned short*)alloc((size_t)NNODES * 256 * 2);
    unsigned short* h1l = (unsigned short*)alloc((size_t)NNODES * 256 * 2);
    float* Wh2 = (float*)alloc((size_t)NNODES * 128 * 4);
    float* as2 = (float*)alloc((size_t)NHEADS * NNODES * 4);
    float* ad2 = (float*)alloc((size_t)NHEADS * NNODES * 4);

    // 1) pack W (tiny)
    pack_b_both_kernel<<<dim3((256 * 512 + 128 * 256) / 256), dim3(256), 0, stream>>>(
        W1, W2, B1h, B1l, B2h, B2l);
    // 2) fused: gemm1(+adot1, BK=32) || build_nbr (8 blocks/CU)
    fused1_kernel<<<dim3(512 + NNODES / 4), dim3(256), 0, stream>>>(
        adj, nbr, deg, x, B1h, B1l, a1, Wh1, as1, ad1);
    // 3) agg1 -> pre-split h1 (hi/lo bf16)
    agg_kernel<64, true><<<dim3(NNODES), dim3(256), 0, stream>>>(
        Wh1, as1, ad1, nbr, deg, nullptr, h1h, h1l);
    // 4) gemm2(+adot2), pre-split A
    gemm2_kernel<<<dim3(NNODES / 32, 2), dim3(256), 0, stream>>>(
        h1h, h1l, B2h, B2l, a2, Wh2, as2, ad2);
    // 5) agg2 -> final output
    agg_kernel<32, false><<<dim3(NNODES), dim3(256), 0, stream>>>(
        Wh2, as2, ad2, nbr, deg, outp, nullptr, nullptr);
}

// Round 11
// 65.672 us; speedup vs baseline: 4.7792x; 1.0059x over previous
//
#include <hip/hip_runtime.h>
#include <hip/hip_bf16.h>
#include <cstdint>
#include <cstddef>

#define NNODES 4096
#define NHEADS 4
#define NBR_STRIDE 128

typedef __attribute__((ext_vector_type(8))) short bf16x8v;
typedef __attribute__((ext_vector_type(4))) float f32x4;

__device__ inline unsigned short bf16_rn(float f) {
    unsigned int u = __float_as_uint(f);
    u += 0x7FFFu + ((u >> 16) & 1u);
    return (unsigned short)(u >> 16);
}
__device__ inline float bf16_f32(unsigned short s) {
    return __uint_as_float(((unsigned int)s) << 16);
}

// ---------------------------------------------------------------------------
// build_nbr body: one wave per row (4 rows per block-call). All 16 float4
// row-loads hoisted to registers before the serial ballot/compaction chain.
// ---------------------------------------------------------------------------
__device__ inline void build_nbr_body(
    const float* __restrict__ adj, int* __restrict__ nbr, int* __restrict__ deg,
    int rowblk) {
    int wave = threadIdx.x >> 6;
    int lane = threadIdx.x & 63;
    int row = rowblk * 4 + wave;
    const float4* arow = reinterpret_cast<const float4*>(adj + (size_t)row * NNODES);
    float4 v[16];
    #pragma unroll
    for (int it = 0; it < 16; ++it) v[it] = arow[it * 64 + lane];
    unsigned long long lt = (1ull << lane) - 1ull;
    int base = 0;
    #pragma unroll
    for (int it = 0; it < 16; ++it) {
        bool b0 = v[it].x > 0.f, b1 = v[it].y > 0.f, b2 = v[it].z > 0.f, b3 = v[it].w > 0.f;
        unsigned long long m0 = __ballot(b0);
        unsigned long long m1 = __ballot(b1);
        unsigned long long m2 = __ballot(b2);
        unsigned long long m3 = __ballot(b3);
        int pre = __popcll(m0 & lt) + __popcll(m1 & lt) +
                  __popcll(m2 & lt) + __popcll(m3 & lt);
        int pos = base + pre;
        int colb = it * 256 + lane * 4;
        if (b0) { if (pos < NBR_STRIDE) nbr[row * NBR_STRIDE + pos] = colb;     pos++; }
        if (b1) { if (pos < NBR_STRIDE) nbr[row * NBR_STRIDE + pos] = colb + 1; pos++; }
        if (b2) { if (pos < NBR_STRIDE) nbr[row * NBR_STRIDE + pos] = colb + 2; pos++; }
        if (b3) { if (pos < NBR_STRIDE) nbr[row * NBR_STRIDE + pos] = colb + 3; pos++; }
        base += __popcll(m0) + __popcll(m1) + __popcll(m2) + __popcll(m3);
    }
    if (lane == 0) deg[row] = base < NBR_STRIDE ? base : NBR_STRIDE;
}

// ---------------------------------------------------------------------------
// Kernel: pack BOTH layers' W -> transposed hi/lo bf16  Bt[N][K]
// ---------------------------------------------------------------------------
__global__ __launch_bounds__(256) void pack_b_both_kernel(
    const float* __restrict__ W1, const float* __restrict__ W2,
    unsigned short* __restrict__ B1h, unsigned short* __restrict__ B1l,
    unsigned short* __restrict__ B2h, unsigned short* __restrict__ B2l) {
    int t = blockIdx.x * 256 + threadIdx.x;
    if (t < 256 * 512) {
        int n = t >> 9, k = t & 511;
        int h = n >> 6, o = n & 63;
        float v = W1[((size_t)h * 512 + k) * 64 + o];
        unsigned short hi = bf16_rn(v);
        B1h[t] = hi;
        B1l[t] = bf16_rn(v - bf16_f32(hi));
    } else {
        int u = t - 256 * 512;
        if (u < 128 * 256) {
            int n = u >> 8, k = u & 255;
            int h = n >> 5, o = n & 31;
            float v = W2[((size_t)h * 256 + k) * 32 + o];
            unsigned short hi = bf16_rn(v);
            B2h[u] = hi;
            B2l[u] = bf16_rn(v - bf16_f32(hi));
        }
    }
}

// ---------------------------------------------------------------------------
// gemm body: C[M,N] = A[M,K] * Bt[N,K]^T via hi*hi+hi*lo+lo*hi bf16 MFMA.
// A either f32 (split in-kernel; ASPLIT=false) or pre-split hi/lo bf16
// (ASPLIT=true). B pre-packed hi/lo. BM=32, BN=64; BK templated (32 or 64).
// Epilogue: C + fused adot. asrc/adst written NODE-MAJOR [n][h].
// ---------------------------------------------------------------------------
template <int K, int N, int FO, int BK, bool ASPLIT>
__device__ inline void gemm_body(
    char* arena,
    const float* __restrict__ A,
    const unsigned short* __restrict__ Ah, const unsigned short* __restrict__ Al,
    const unsigned short* __restrict__ Bh, const unsigned short* __restrict__ Bl,
    const float* __restrict__ a, float* __restrict__ C,
    float* __restrict__ asrc, float* __restrict__ adst,
    int bx, int by) {
    constexpr int BM = 32, BN = 64, LP = BK + 8;
    constexpr int ALD = BM * LP * 2;
    constexpr int BLD = BN * LP * 2;
    typedef unsigned short (*lds_t)[LP];
    lds_t Alh = (lds_t)(arena);
    lds_t All = (lds_t)(arena + ALD);
    lds_t Blh = (lds_t)(arena + 2 * ALD);
    lds_t Bll = (lds_t)(arena + 2 * ALD + BLD);
    float* reds = (float*)(arena + 2 * ALD + 2 * BLD);          // [2][32]
    float* redd = (float*)(arena + 2 * ALD + 2 * BLD + 256);    // [2][32]
    int tid = threadIdx.x;
    int wave = tid >> 6, lane = tid & 63;
    int rowBase = bx * BM;
    int colBase = by * BN;
    int wr = wave >> 1, wc = wave & 1;
    int lr = lane & 15, lk = lane >> 4;
    f32x4 acc0 = {0.f, 0.f, 0.f, 0.f};
    f32x4 acc1 = {0.f, 0.f, 0.f, 0.f};

    for (int k0 = 0; k0 < K; k0 += BK) {
        if constexpr (BK == 32) {
            int ar = tid >> 3, acf = (tid & 7) * 4;     // A: 32x32
            int br = tid >> 2, bc = (tid & 3) * 8;      // B: 64x32
            uint4 bh = *reinterpret_cast<const uint4*>(&Bh[(size_t)(colBase + br) * K + k0 + bc]);
            uint4 bl = *reinterpret_cast<const uint4*>(&Bl[(size_t)(colBase + br) * K + k0 + bc]);
            if constexpr (ASPLIT) {
                uint2 avh = *reinterpret_cast<const uint2*>(&Ah[(size_t)(rowBase + ar) * K + k0 + acf]);
                uint2 avl = *reinterpret_cast<const uint2*>(&Al[(size_t)(rowBase + ar) * K + k0 + acf]);
                __syncthreads();
                *reinterpret_cast<uint2*>(&Alh[ar][acf]) = avh;
                *reinterpret_cast<uint2*>(&All[ar][acf]) = avl;
                *reinterpret_cast<uint4*>(&Blh[br][bc]) = bh;
                *reinterpret_cast<uint4*>(&Bll[br][bc]) = bl;
            } else {
                float4 a0 = *reinterpret_cast<const float4*>(&A[(size_t)(rowBase + ar) * K + k0 + acf]);
                __syncthreads();
                ushort4 h4, l4;
                h4.x = bf16_rn(a0.x); l4.x = bf16_rn(a0.x - bf16_f32(h4.x));
                h4.y = bf16_rn(a0.y); l4.y = bf16_rn(a0.y - bf16_f32(h4.y));
                h4.z = bf16_rn(a0.z); l4.z = bf16_rn(a0.z - bf16_f32(h4.z));
                h4.w = bf16_rn(a0.w); l4.w = bf16_rn(a0.w - bf16_f32(h4.w));
                *reinterpret_cast<ushort4*>(&Alh[ar][acf]) = h4;
                *reinterpret_cast<ushort4*>(&All[ar][acf]) = l4;
                *reinterpret_cast<uint4*>(&Blh[br][bc]) = bh;
                *reinterpret_cast<uint4*>(&Bll[br][bc]) = bl;
            }
        } else {   // BK == 64
            int ar = tid >> 3, ac = (tid & 7) * 8;
            uint4 bh0 = *reinterpret_cast<const uint4*>(&Bh[(size_t)(colBase + ar) * K + k0 + ac]);
            uint4 bl0 = *reinterpret_cast<const uint4*>(&Bl[(size_t)(colBase + ar) * K + k0 + ac]);
            uint4 bh1 = *reinterpret_cast<const uint4*>(&Bh[(size_t)(colBase + 32 + ar) * K + k0 + ac]);
            uint4 bl1 = *reinterpret_cast<const uint4*>(&Bl[(size_t)(colBase + 32 + ar) * K + k0 + ac]);
            if constexpr (ASPLIT) {
                uint4 avh = *reinterpret_cast<const uint4*>(&Ah[(size_t)(rowBase + ar) * K + k0 + ac]);
                uint4 avl = *reinterpret_cast<const uint4*>(&Al[(size_t)(rowBase + ar) * K + k0 + ac]);
                __syncthreads();
                *reinterpret_cast<uint4*>(&Alh[ar][ac]) = avh;
                *reinterpret_cast<uint4*>(&All[ar][ac]) = avl;
                *reinterpret_cast<uint4*>(&Blh[ar][ac]) = bh0;
                *reinterpret_cast<uint4*>(&Bll[ar][ac]) = bl0;
                *reinterpret_cast<uint4*>(&Blh[32 + ar][ac]) = bh1;
                *reinterpret_cast<uint4*>(&Bll[32 + ar][ac]) = bl1;
            } else {
                float4 a0 = *reinterpret_cast<const float4*>(&A[(size_t)(rowBase + ar) * K + k0 + ac]);
                float4 a1 = *reinterpret_cast<const float4*>(&A[(size_t)(rowBase + ar) * K + k0 + ac + 4]);
                __syncthreads();
                ushort4 h4, l4;
                h4.x = bf16_rn(a0.x); l4.x = bf16_rn(a0.x - bf16_f32(h4.x));
                h4.y = bf16_rn(a0.y); l4.y = bf16_rn(a0.y - bf16_f32(h4.y));
                h4.z = bf16_rn(a0.z); l4.z = bf16_rn(a0.z - bf16_f32(h4.z));
                h4.w = bf16_rn(a0.w); l4.w = bf16_rn(a0.w - bf16_f32(h4.w));
                *reinterpret_cast<ushort4*>(&Alh[ar][ac]) = h4;
                *reinterpret_cast<ushort4*>(&All[ar][ac]) = l4;
                h4.x = bf16_rn(a1.x); l4.x = bf16_rn(a1.x - bf16_f32(h4.x));
                h4.y = bf16_rn(a1.y); l4.y = bf16_rn(a1.y - bf16_f32(h4.y));
                h4.z = bf16_rn(a1.z); l4.z = bf16_rn(a1.z - bf16_f32(h4.z));
                h4.w = bf16_rn(a1.w); l4.w = bf16_rn(a1.w - bf16_f32(h4.w));
                *reinterpret_cast<ushort4*>(&Alh[ar][ac + 4]) = h4;
                *reinterpret_cast<ushort4*>(&All[ar][ac + 4]) = l4;
                *reinterpret_cast<uint4*>(&Blh[ar][ac]) = bh0;
                *reinterpret_cast<uint4*>(&Bll[ar][ac]) = bl0;
                *reinterpret_cast<uint4*>(&Blh[32 + ar][ac]) = bh1;
                *reinterpret_cast<uint4*>(&Bll[32 + ar][ac]) = bl1;
            }
        }
        __syncthreads();
        #pragma unroll
        for (int ks = 0; ks < BK / 32; ++ks) {
            int kb = ks * 32 + lk * 8;
            bf16x8v ah = *reinterpret_cast<const bf16x8v*>(&Alh[wr * 16 + lr][kb]);
            bf16x8v al = *reinterpret_cast<const bf16x8v*>(&All[wr * 16 + lr][kb]);
            bf16x8v b0h = *reinterpret_cast<const bf16x8v*>(&Blh[wc * 32 + lr][kb]);
            bf16x8v b0l = *reinterpret_cast<const bf16x8v*>(&Bll[wc * 32 + lr][kb]);
            bf16x8v b1h = *reinterpret_cast<const bf16x8v*>(&Blh[wc * 32 + 16 + lr][kb]);
            bf16x8v b1l = *reinterpret_cast<const bf16x8v*>(&Bll[wc * 32 + 16 + lr][kb]);
            acc0 = __builtin_amdgcn_mfma_f32_16x16x32_bf16(ah, b0h, acc0, 0, 0, 0);
            acc0 = __builtin_amdgcn_mfma_f32_16x16x32_bf16(ah, b0l, acc0, 0, 0, 0);
            acc0 = __builtin_amdgcn_mfma_f32_16x16x32_bf16(al, b0h, acc0, 0, 0, 0);
            acc1 = __builtin_amdgcn_mfma_f32_16x16x32_bf16(ah, b1h, acc1, 0, 0, 0);
            acc1 = __builtin_amdgcn_mfma_f32_16x16x32_bf16(ah, b1l, acc1, 0, 0, 0);
            acc1 = __builtin_amdgcn_mfma_f32_16x16x32_bf16(al, b1h, acc1, 0, 0, 0);
        }
    }
    // ---- write C ----
    int crow = rowBase + wr * 16 + lk * 4;
    int ccol = colBase + wc * 32 + lr;
    #pragma unroll
    for (int r = 0; r < 4; ++r) {
        C[(size_t)(crow + r) * N + ccol]      = acc0[r];
        C[(size_t)(crow + r) * N + ccol + 16] = acc1[r];
    }
    // ---- fused adot epilogue (node-major [n][h] outputs) ----
    int n0 = colBase + wc * 32 + lr;
    int hh = n0 / FO;
    int o0 = n0 % FO;
    int o1 = o0 + 16;
    const float* av = a + hh * 2 * FO;
    float aS0 = av[o0], aS1 = av[o1];
    float aD0 = av[FO + o0], aD1 = av[FO + o1];
    float sv[4], dv[4];
    #pragma unroll
    for (int r = 0; r < 4; ++r) {
        sv[r] = acc0[r] * aS0 + acc1[r] * aS1;
        dv[r] = acc0[r] * aD0 + acc1[r] * aD1;
        #pragma unroll
        for (int msk = 1; msk < 16; msk <<= 1) {
            sv[r] += __shfl_xor(sv[r], msk);
            dv[r] += __shfl_xor(dv[r], msk);
        }
    }
    if constexpr (FO == 64) {
        if (lr == 0) {
            #pragma unroll
            for (int r = 0; r < 4; ++r) {
                reds[wc * 32 + wr * 16 + lk * 4 + r] = sv[r];
                redd[wc * 32 + wr * 16 + lk * 4 + r] = dv[r];
            }
        }
        __syncthreads();
        if (tid < BM) {
            int row = tid;
            asrc[(size_t)(rowBase + row) * NHEADS + by] = reds[row] + reds[32 + row];
            adst[(size_t)(rowBase + row) * NHEADS + by] = redd[row] + redd[32 + row];
        }
    } else {
        if (lr == 0) {
            #pragma unroll
            for (int r = 0; r < 4; ++r) {
                int row = rowBase + wr * 16 + lk * 4 + r;
                asrc[(size_t)row * NHEADS + hh] = sv[r];
                adst[(size_t)row * NHEADS + hh] = dv[r];
            }
        }
    }
}

// ---------------------------------------------------------------------------
// Fused kernel: blocks [0,512) = gemm1 tiles (BK=32 -> 15.9KB LDS);
// [512,1536) = nbr (4 rows each).
// ---------------------------------------------------------------------------
__global__ __launch_bounds__(256) void fused1_kernel(
    const float* __restrict__ adj, int* __restrict__ nbr, int* __restrict__ deg,
    const float* __restrict__ x,
    const unsigned short* __restrict__ B1h, const unsigned short* __restrict__ B1l,
    const float* __restrict__ a1, float* __restrict__ Wh1,
    float* __restrict__ as1, float* __restrict__ ad1) {
    __shared__ __align__(16) char arena[15872];
    int b = blockIdx.x;
    if (b < 512) {
        gemm_body<512, 256, 64, 32, false>(arena, x, nullptr, nullptr,
                                           B1h, B1l, a1, Wh1, as1, ad1,
                                           b & 127, b >> 7);
    } else {
        build_nbr_body(adj, nbr, deg, b - 512);
    }
}

// ---------------------------------------------------------------------------
// Standalone gemm (layer 2): pre-split A (h1h/h1l), BK=64.
// ---------------------------------------------------------------------------
__global__ __launch_bounds__(256) void gemm2_kernel(
    const unsigned short* __restrict__ Ah, const unsigned short* __restrict__ Al,
    const unsigned short* __restrict__ Bh, const unsigned short* __restrict__ Bl,
    const float* __restrict__ a, float* __restrict__ C,
    float* __restrict__ asrc, float* __restrict__ adst) {
    __shared__ __align__(16) char arena[28160];
    gemm_body<256, 128, 32, 64, true>(arena, nullptr, Ah, Al, Bh, Bl,
                                      a, C, asrc, adst, blockIdx.x, blockIdx.y);
}

// ---------------------------------------------------------------------------
// agg: sparse softmax + aggregation + ELU. One block per node; wave w = head w.
// asrc/adst node-major [n][h]: 4 heads share one 16B chunk -> 1 L2 line per
// edge (was 4) and L1 hits for waves 2-4. Tail loop fully unrolled+guarded.
// ---------------------------------------------------------------------------
template <int FO, bool SPLITOUT>
__global__ __launch_bounds__(256) void agg_kernel(
    const float* __restrict__ Wh,
    const float* __restrict__ asrc, const float* __restrict__ adst,
    const int* __restrict__ nbr, const int* __restrict__ deg,
    float* __restrict__ out,
    unsigned short* __restrict__ outh, unsigned short* __restrict__ outl) {
    __shared__ float2 sw[4][NBR_STRIDE];
    int wslot = threadIdx.x >> 6;
    int lane = threadIdx.x & 63;
    int n = blockIdx.x;
    int h = wslot;
    int dg = deg[n];
    const int* lst = nbr + n * NBR_STRIDE;
    float my_as = asrc[(size_t)n * NHEADS + h];

    int c0 = 0, c1 = 0;
    float e0 = -1e30f, e1 = -1e30f;
    if (lane < dg) {
        c0 = lst[lane];
        float e = my_as + adst[(size_t)c0 * NHEADS + h];
        e0 = e >= 0.f ? e : 0.2f * e;
    }
    if (lane + 64 < dg) {
        c1 = lst[lane + 64];
        float e = my_as + adst[(size_t)c1 * NHEADS + h];
        e1 = e >= 0.f ? e : 0.2f * e;
    }
    float m = fmaxf(e0, e1);
    #pragma unroll
    for (int s = 32; s; s >>= 1) m = fmaxf(m, __shfl_xor(m, s));
    float p0 = (lane < dg) ? __expf(e0 - m) : 0.f;
    float p1 = (lane + 64 < dg) ? __expf(e1 - m) : 0.f;
    float denom = p0 + p1;
    #pragma unroll
    for (int s = 32; s; s >>= 1) denom += __shfl_xor(denom, s);
    float inv = 1.0f / denom;

    if (lane < dg)      sw[wslot][lane]      = make_float2(p0 * inv, __int_as_float(c0));
    if (lane + 64 < dg) sw[wslot][lane + 64] = make_float2(p1 * inv, __int_as_float(c1));

    constexpr int STRIDE = NHEADS * FO;
    constexpr int LPR = FO / 4;      // lanes per neighbor row (16 or 8)
    constexpr int NPS = 64 / LPR;    // neighbors per step (4 or 8)
    int sub = lane / LPR;
    int dim4 = (lane % LPR) * 4;
    const float* whp = Wh + h * FO + dim4;
    f32x4 acc = {0.f, 0.f, 0.f, 0.f};
    int main_n = (dg / (8 * NPS)) * (8 * NPS);
    int k = 0;
    for (; k < main_n; k += 8 * NPS) {
        #pragma unroll
        for (int u = 0; u < 8; ++u) {
            float2 w = sw[wslot][k + u * NPS + sub];
            int col = __float_as_int(w.y);
            float4 v = *reinterpret_cast<const float4*>(&whp[(size_t)col * STRIDE]);
            acc[0] += w.x * v.x;
            acc[1] += w.x * v.y;
            acc[2] += w.x * v.z;
            acc[3] += w.x * v.w;
        }
    }
    // tail: fully unrolled + guarded so the remaining gathers pipeline
    #pragma unroll
    for (int u = 0; u < 8; ++u) {
        int kk = main_n + u * NPS + sub;
        if (kk < dg) {
            float2 w = sw[wslot][kk];
            int col = __float_as_int(w.y);
            float4 v = *reinterpret_cast<const float4*>(&whp[(size_t)col * STRIDE]);
            acc[0] += w.x * v.x;
            acc[1] += w.x * v.y;
            acc[2] += w.x * v.z;
            acc[3] += w.x * v.w;
        }
    }
    #pragma unroll
    for (int s = LPR; s < 64; s <<= 1) {
        acc[0] += __shfl_xor(acc[0], s);
        acc[1] += __shfl_xor(acc[1], s);
        acc[2] += __shfl_xor(acc[2], s);
        acc[3] += __shfl_xor(acc[3], s);
    }
    if (lane < LPR) {
        float r0 = acc[0] > 0.f ? acc[0] : expm1f(acc[0]);
        float r1 = acc[1] > 0.f ? acc[1] : expm1f(acc[1]);
        float r2 = acc[2] > 0.f ? acc[2] : expm1f(acc[2]);
        float r3 = acc[3] > 0.f ? acc[3] : expm1f(acc[3]);
        size_t idx = (size_t)n * STRIDE + h * FO + dim4;
        if constexpr (SPLITOUT) {
            ushort4 hv, lv;
            hv.x = bf16_rn(r0); lv.x = bf16_rn(r0 - bf16_f32(hv.x));
            hv.y = bf16_rn(r1); lv.y = bf16_rn(r1 - bf16_f32(hv.y));
            hv.z = bf16_rn(r2); lv.z = bf16_rn(r2 - bf16_f32(hv.z));
            hv.w = bf16_rn(r3); lv.w = bf16_rn(r3 - bf16_f32(hv.w));
            *reinterpret_cast<ushort4*>(&outh[idx]) = hv;
            *reinterpret_cast<ushort4*>(&outl[idx]) = lv;
        } else {
            *reinterpret_cast<float4*>(&out[idx]) = make_float4(r0, r1, r2, r3);
        }
    }
}

// ---------------------------------------------------------------------------
extern "C" void kernel_launch(void* const* d_in, const int* in_sizes, int n_in,
                              void* d_out, int out_size, void* d_ws, size_t ws_size,
                              hipStream_t stream) {
    const float* x   = (const float*)d_in[0];
    const float* adj = (const float*)d_in[1];
    const float* W1  = (const float*)d_in[2];
    const float* a1  = (const float*)d_in[3];
    const float* W2  = (const float*)d_in[4];
    const float* a2  = (const float*)d_in[5];
    float* outp = (float*)d_out;

    char* p = (char*)d_ws;
    auto alloc = [&](size_t bytes) -> void* {
        void* r = (void*)p;
        p += (bytes + 255) & ~(size_t)255;
        return r;
    };
    int*   nbr = (int*)alloc((size_t)NNODES * NBR_STRIDE * 4);
    int*   deg = (int*)alloc((size_t)NNODES * 4);
    unsigned short* B1h = (unsigned short*)alloc((size_t)256 * 512 * 2);
    unsigned short* B1l = (unsigned short*)alloc((size_t)256 * 512 * 2);
    unsigned short* B2h = (unsigned short*)alloc((size_t)128 * 256 * 2);
    unsigned short* B2l = (unsigned short*)alloc((size_t)128 * 256 * 2);
    float* Wh1 = (float*)alloc((size_t)NNODES * 256 * 4);
    float* as1 = (float*)alloc((size_t)NHEADS * NNODES * 4);
    float* ad1 = (float*)alloc((size_t)NHEADS * NNODES * 4);
    unsigned short* h1h = (unsigned short*)alloc((size_t)NNODES * 256 * 2);
    unsigned short* h1l = (unsigned short*)alloc((size_t)NNODES * 256 * 2);
    float* Wh2 = (float*)alloc((size_t)NNODES * 128 * 4);
    float* as2 = (float*)alloc((size_t)NHEADS * NNODES * 4);
    float* ad2 = (float*)alloc((size_t)NHEADS * NNODES * 4);

    // 1) pack W (tiny)
    pack_b_both_kernel<<<dim3((256 * 512 + 128 * 256) / 256), dim3(256), 0, stream>>>(
        W1, W2, B1h, B1l, B2h, B2l);
    // 2) fused: gemm1(+adot1, BK=32) || build_nbr
    fused1_kernel<<<dim3(512 + NNODES / 4), dim3(256), 0, stream>>>(
        adj, nbr, deg, x, B1h, B1l, a1, Wh1, as1, ad1);
    // 3) agg1 -> pre-split h1 (hi/lo bf16)
    agg_kernel<64, true><<<dim3(NNODES), dim3(256), 0, stream>>>(
        Wh1, as1, ad1, nbr, deg, nullptr, h1h, h1l);
    // 4) gemm2(+adot2), pre-split A
    gemm2_kernel<<<dim3(NNODES / 32, 2), dim3(256), 0, stream>>>(
        h1h, h1l, B2h, B2l, a2, Wh2, as2, ad2);
    // 5) agg2 -> final output
    agg_kernel<32, false><<<dim3(NNODES), dim3(256), 0, stream>>>(
        Wh2, as2, ad2, nbr, deg, outp, nullptr, nullptr);
}

// Round 12
// 64.945 us; speedup vs baseline: 4.8327x; 1.0112x over previous
//
#include <hip/hip_runtime.h>
#include <hip/hip_bf16.h>
#include <cstdint>
#include <cstddef>

#define NNODES 4096
#define NHEADS 4
#define NBR_STRIDE 128

typedef __attribute__((ext_vector_type(8))) short bf16x8v;
typedef __attribute__((ext_vector_type(4))) float f32x4;

__device__ inline unsigned short bf16_rn(float f) {
    unsigned int u = __float_as_uint(f);
    u += 0x7FFFu + ((u >> 16) & 1u);
    return (unsigned short)(u >> 16);
}
__device__ inline float bf16_f32(unsigned short s) {
    return __uint_as_float(((unsigned int)s) << 16);
}

// ---------------------------------------------------------------------------
// build_nbr body: one wave per row (4 rows per block-call). All 16 float4
// row-loads hoisted to registers before the serial ballot/compaction chain.
// ---------------------------------------------------------------------------
__device__ inline void build_nbr_body(
    const float* __restrict__ adj, int* __restrict__ nbr, int* __restrict__ deg,
    int rowblk) {
    int wave = threadIdx.x >> 6;
    int lane = threadIdx.x & 63;
    int row = rowblk * 4 + wave;
    const float4* arow = reinterpret_cast<const float4*>(adj + (size_t)row * NNODES);
    float4 v[16];
    #pragma unroll
    for (int it = 0; it < 16; ++it) v[it] = arow[it * 64 + lane];
    unsigned long long lt = (1ull << lane) - 1ull;
    int base = 0;
    #pragma unroll
    for (int it = 0; it < 16; ++it) {
        bool b0 = v[it].x > 0.f, b1 = v[it].y > 0.f, b2 = v[it].z > 0.f, b3 = v[it].w > 0.f;
        unsigned long long m0 = __ballot(b0);
        unsigned long long m1 = __ballot(b1);
        unsigned long long m2 = __ballot(b2);
        unsigned long long m3 = __ballot(b3);
        int pre = __popcll(m0 & lt) + __popcll(m1 & lt) +
                  __popcll(m2 & lt) + __popcll(m3 & lt);
        int pos = base + pre;
        int colb = it * 256 + lane * 4;
        if (b0) { if (pos < NBR_STRIDE) nbr[row * NBR_STRIDE + pos] = colb;     pos++; }
        if (b1) { if (pos < NBR_STRIDE) nbr[row * NBR_STRIDE + pos] = colb + 1; pos++; }
        if (b2) { if (pos < NBR_STRIDE) nbr[row * NBR_STRIDE + pos] = colb + 2; pos++; }
        if (b3) { if (pos < NBR_STRIDE) nbr[row * NBR_STRIDE + pos] = colb + 3; pos++; }
        base += __popcll(m0) + __popcll(m1) + __popcll(m2) + __popcll(m3);
    }
    if (lane == 0) deg[row] = base < NBR_STRIDE ? base : NBR_STRIDE;
}

// ---------------------------------------------------------------------------
// Kernel: pack BOTH layers' W -> transposed hi/lo bf16  Bt[N][K]
// ---------------------------------------------------------------------------
__global__ __launch_bounds__(256) void pack_b_both_kernel(
    const float* __restrict__ W1, const float* __restrict__ W2,
    unsigned short* __restrict__ B1h, unsigned short* __restrict__ B1l,
    unsigned short* __restrict__ B2h, unsigned short* __restrict__ B2l) {
    int t = blockIdx.x * 256 + threadIdx.x;
    if (t < 256 * 512) {
        int n = t >> 9, k = t & 511;
        int h = n >> 6, o = n & 63;
        float v = W1[((size_t)h * 512 + k) * 64 + o];
        unsigned short hi = bf16_rn(v);
        B1h[t] = hi;
        B1l[t] = bf16_rn(v - bf16_f32(hi));
    } else {
        int u = t - 256 * 512;
        if (u < 128 * 256) {
            int n = u >> 8, k = u & 255;
            int h = n >> 5, o = n & 31;
            float v = W2[((size_t)h * 256 + k) * 32 + o];
            unsigned short hi = bf16_rn(v);
            B2h[u] = hi;
            B2l[u] = bf16_rn(v - bf16_f32(hi));
        }
    }
}

// ---------------------------------------------------------------------------
// gemm body: C[M,N] = A[M,K] * Bt[N,K]^T via hi*hi+hi*lo+lo*hi bf16 MFMA.
// A either f32 (split in-kernel; ASPLIT=false) or pre-split hi/lo bf16
// (ASPLIT=true). B pre-packed hi/lo. BM=32, BN=64; BK templated (32 or 64).
// Epilogue: C + fused adot. asrc/adst written NODE-MAJOR [n][h].
// ---------------------------------------------------------------------------
template <int K, int N, int FO, int BK, bool ASPLIT>
__device__ inline void gemm_body(
    char* arena,
    const float* __restrict__ A,
    const unsigned short* __restrict__ Ah, const unsigned short* __restrict__ Al,
    const unsigned short* __restrict__ Bh, const unsigned short* __restrict__ Bl,
    const float* __restrict__ a, float* __restrict__ C,
    float* __restrict__ asrc, float* __restrict__ adst,
    int bx, int by) {
    constexpr int BM = 32, BN = 64, LP = BK + 8;
    constexpr int ALD = BM * LP * 2;
    constexpr int BLD = BN * LP * 2;
    typedef unsigned short (*lds_t)[LP];
    lds_t Alh = (lds_t)(arena);
    lds_t All = (lds_t)(arena + ALD);
    lds_t Blh = (lds_t)(arena + 2 * ALD);
    lds_t Bll = (lds_t)(arena + 2 * ALD + BLD);
    float* reds = (float*)(arena + 2 * ALD + 2 * BLD);          // [2][32]
    float* redd = (float*)(arena + 2 * ALD + 2 * BLD + 256);    // [2][32]
    int tid = threadIdx.x;
    int wave = tid >> 6, lane = tid & 63;
    int rowBase = bx * BM;
    int colBase = by * BN;
    int wr = wave >> 1, wc = wave & 1;
    int lr = lane & 15, lk = lane >> 4;
    f32x4 acc0 = {0.f, 0.f, 0.f, 0.f};
    f32x4 acc1 = {0.f, 0.f, 0.f, 0.f};

    for (int k0 = 0; k0 < K; k0 += BK) {
        if constexpr (BK == 32) {
            int ar = tid >> 3, acf = (tid & 7) * 4;     // A: 32x32
            int br = tid >> 2, bc = (tid & 3) * 8;      // B: 64x32
            uint4 bh = *reinterpret_cast<const uint4*>(&Bh[(size_t)(colBase + br) * K + k0 + bc]);
            uint4 bl = *reinterpret_cast<const uint4*>(&Bl[(size_t)(colBase + br) * K + k0 + bc]);
            if constexpr (ASPLIT) {
                uint2 avh = *reinterpret_cast<const uint2*>(&Ah[(size_t)(rowBase + ar) * K + k0 + acf]);
                uint2 avl = *reinterpret_cast<const uint2*>(&Al[(size_t)(rowBase + ar) * K + k0 + acf]);
                __syncthreads();
                *reinterpret_cast<uint2*>(&Alh[ar][acf]) = avh;
                *reinterpret_cast<uint2*>(&All[ar][acf]) = avl;
                *reinterpret_cast<uint4*>(&Blh[br][bc]) = bh;
                *reinterpret_cast<uint4*>(&Bll[br][bc]) = bl;
            } else {
                float4 a0 = *reinterpret_cast<const float4*>(&A[(size_t)(rowBase + ar) * K + k0 + acf]);
                __syncthreads();
                ushort4 h4, l4;
                h4.x = bf16_rn(a0.x); l4.x = bf16_rn(a0.x - bf16_f32(h4.x));
                h4.y = bf16_rn(a0.y); l4.y = bf16_rn(a0.y - bf16_f32(h4.y));
                h4.z = bf16_rn(a0.z); l4.z = bf16_rn(a0.z - bf16_f32(h4.z));
                h4.w = bf16_rn(a0.w); l4.w = bf16_rn(a0.w - bf16_f32(h4.w));
                *reinterpret_cast<ushort4*>(&Alh[ar][acf]) = h4;
                *reinterpret_cast<ushort4*>(&All[ar][acf]) = l4;
                *reinterpret_cast<uint4*>(&Blh[br][bc]) = bh;
                *reinterpret_cast<uint4*>(&Bll[br][bc]) = bl;
            }
        } else {   // BK == 64
            int ar = tid >> 3, ac = (tid & 7) * 8;
            uint4 bh0 = *reinterpret_cast<const uint4*>(&Bh[(size_t)(colBase + ar) * K + k0 + ac]);
            uint4 bl0 = *reinterpret_cast<const uint4*>(&Bl[(size_t)(colBase + ar) * K + k0 + ac]);
            uint4 bh1 = *reinterpret_cast<const uint4*>(&Bh[(size_t)(colBase + 32 + ar) * K + k0 + ac]);
            uint4 bl1 = *reinterpret_cast<const uint4*>(&Bl[(size_t)(colBase + 32 + ar) * K + k0 + ac]);
            if constexpr (ASPLIT) {
                uint4 avh = *reinterpret_cast<const uint4*>(&Ah[(size_t)(rowBase + ar) * K + k0 + ac]);
                uint4 avl = *reinterpret_cast<const uint4*>(&Al[(size_t)(rowBase + ar) * K + k0 + ac]);
                __syncthreads();
                *reinterpret_cast<uint4*>(&Alh[ar][ac]) = avh;
                *reinterpret_cast<uint4*>(&All[ar][ac]) = avl;
                *reinterpret_cast<uint4*>(&Blh[ar][ac]) = bh0;
                *reinterpret_cast<uint4*>(&Bll[ar][ac]) = bl0;
                *reinterpret_cast<uint4*>(&Blh[32 + ar][ac]) = bh1;
                *reinterpret_cast<uint4*>(&Bll[32 + ar][ac]) = bl1;
            } else {
                float4 a0 = *reinterpret_cast<const float4*>(&A[(size_t)(rowBase + ar) * K + k0 + ac]);
                float4 a1 = *reinterpret_cast<const float4*>(&A[(size_t)(rowBase + ar) * K + k0 + ac + 4]);
                __syncthreads();
                ushort4 h4, l4;
                h4.x = bf16_rn(a0.x); l4.x = bf16_rn(a0.x - bf16_f32(h4.x));
                h4.y = bf16_rn(a0.y); l4.y = bf16_rn(a0.y - bf16_f32(h4.y));
                h4.z = bf16_rn(a0.z); l4.z = bf16_rn(a0.z - bf16_f32(h4.z));
                h4.w = bf16_rn(a0.w); l4.w = bf16_rn(a0.w - bf16_f32(h4.w));
                *reinterpret_cast<ushort4*>(&Alh[ar][ac]) = h4;
                *reinterpret_cast<ushort4*>(&All[ar][ac]) = l4;
                h4.x = bf16_rn(a1.x); l4.x = bf16_rn(a1.x - bf16_f32(h4.x));
                h4.y = bf16_rn(a1.y); l4.y = bf16_rn(a1.y - bf16_f32(h4.y));
                h4.z = bf16_rn(a1.z); l4.z = bf16_rn(a1.z - bf16_f32(h4.z));
                h4.w = bf16_rn(a1.w); l4.w = bf16_rn(a1.w - bf16_f32(h4.w));
                *reinterpret_cast<ushort4*>(&Alh[ar][ac + 4]) = h4;
                *reinterpret_cast<ushort4*>(&All[ar][ac + 4]) = l4;
                *reinterpret_cast<uint4*>(&Blh[ar][ac]) = bh0;
                *reinterpret_cast<uint4*>(&Bll[ar][ac]) = bl0;
                *reinterpret_cast<uint4*>(&Blh[32 + ar][ac]) = bh1;
                *reinterpret_cast<uint4*>(&Bll[32 + ar][ac]) = bl1;
            }
        }
        __syncthreads();
        #pragma unroll
        for (int ks = 0; ks < BK / 32; ++ks) {
            int kb = ks * 32 + lk * 8;
            bf16x8v ah = *reinterpret_cast<const bf16x8v*>(&Alh[wr * 16 + lr][kb]);
            bf16x8v al = *reinterpret_cast<const bf16x8v*>(&All[wr * 16 + lr][kb]);
            bf16x8v b0h = *reinterpret_cast<const bf16x8v*>(&Blh[wc * 32 + lr][kb]);
            bf16x8v b0l = *reinterpret_cast<const bf16x8v*>(&Bll[wc * 32 + lr][kb]);
            bf16x8v b1h = *reinterpret_cast<const bf16x8v*>(&Blh[wc * 32 + 16 + lr][kb]);
            bf16x8v b1l = *reinterpret_cast<const bf16x8v*>(&Bll[wc * 32 + 16 + lr][kb]);
            acc0 = __builtin_amdgcn_mfma_f32_16x16x32_bf16(ah, b0h, acc0, 0, 0, 0);
            acc0 = __builtin_amdgcn_mfma_f32_16x16x32_bf16(ah, b0l, acc0, 0, 0, 0);
            acc0 = __builtin_amdgcn_mfma_f32_16x16x32_bf16(al, b0h, acc0, 0, 0, 0);
            acc1 = __builtin_amdgcn_mfma_f32_16x16x32_bf16(ah, b1h, acc1, 0, 0, 0);
            acc1 = __builtin_amdgcn_mfma_f32_16x16x32_bf16(ah, b1l, acc1, 0, 0, 0);
            acc1 = __builtin_amdgcn_mfma_f32_16x16x32_bf16(al, b1h, acc1, 0, 0, 0);
        }
    }
    // ---- write C ----
    int crow = rowBase + wr * 16 + lk * 4;
    int ccol = colBase + wc * 32 + lr;
    #pragma unroll
    for (int r = 0; r < 4; ++r) {
        C[(size_t)(crow + r) * N + ccol]      = acc0[r];
        C[(size_t)(crow + r) * N + ccol + 16] = acc1[r];
    }
    // ---- fused adot epilogue (node-major [n][h] outputs) ----
    int n0 = colBase + wc * 32 + lr;
    int hh = n0 / FO;
    int o0 = n0 % FO;
    int o1 = o0 + 16;
    const float* av = a + hh * 2 * FO;
    float aS0 = av[o0], aS1 = av[o1];
    float aD0 = av[FO + o0], aD1 = av[FO + o1];
    float sv[4], dv[4];
    #pragma unroll
    for (int r = 0; r < 4; ++r) {
        sv[r] = acc0[r] * aS0 + acc1[r] * aS1;
        dv[r] = acc0[r] * aD0 + acc1[r] * aD1;
        #pragma unroll
        for (int msk = 1; msk < 16; msk <<= 1) {
            sv[r] += __shfl_xor(sv[r], msk);
            dv[r] += __shfl_xor(dv[r], msk);
        }
    }
    if constexpr (FO == 64) {
        if (lr == 0) {
            #pragma unroll
            for (int r = 0; r < 4; ++r) {
                reds[wc * 32 + wr * 16 + lk * 4 + r] = sv[r];
                redd[wc * 32 + wr * 16 + lk * 4 + r] = dv[r];
            }
        }
        __syncthreads();
        if (tid < BM) {
            int row = tid;
            asrc[(size_t)(rowBase + row) * NHEADS + by] = reds[row] + reds[32 + row];
            adst[(size_t)(rowBase + row) * NHEADS + by] = redd[row] + redd[32 + row];
        }
    } else {
        if (lr == 0) {
            #pragma unroll
            for (int r = 0; r < 4; ++r) {
                int row = rowBase + wr * 16 + lk * 4 + r;
                asrc[(size_t)row * NHEADS + hh] = sv[r];
                adst[(size_t)row * NHEADS + hh] = dv[r];
            }
        }
    }
}

// ---------------------------------------------------------------------------
// Fused kernel: blocks [0,512) = gemm1 tiles (BK=32 -> 15.9KB LDS);
// [512,1536) = nbr (4 rows each).
// ---------------------------------------------------------------------------
__global__ __launch_bounds__(256) void fused1_kernel(
    const float* __restrict__ adj, int* __restrict__ nbr, int* __restrict__ deg,
    const float* __restrict__ x,
    const unsigned short* __restrict__ B1h, const unsigned short* __restrict__ B1l,
    const float* __restrict__ a1, float* __restrict__ Wh1,
    float* __restrict__ as1, float* __restrict__ ad1) {
    __shared__ __align__(16) char arena[15872];
    int b = blockIdx.x;
    if (b < 512) {
        gemm_body<512, 256, 64, 32, false>(arena, x, nullptr, nullptr,
                                           B1h, B1l, a1, Wh1, as1, ad1,
                                           b & 127, b >> 7);
    } else {
        build_nbr_body(adj, nbr, deg, b - 512);
    }
}

// ---------------------------------------------------------------------------
// Standalone gemm (layer 2): pre-split A (h1h/h1l), BK=64.
// ---------------------------------------------------------------------------
__global__ __launch_bounds__(256) void gemm2_kernel(
    const unsigned short* __restrict__ Ah, const unsigned short* __restrict__ Al,
    const unsigned short* __restrict__ Bh, const unsigned short* __restrict__ Bl,
    const float* __restrict__ a, float* __restrict__ C,
    float* __restrict__ asrc, float* __restrict__ adst) {
    __shared__ __align__(16) char arena[28160];
    gemm_body<256, 128, 32, 64, true>(arena, nullptr, Ah, Al, Bh, Bl,
                                      a, C, asrc, adst, blockIdx.x, blockIdx.y);
}

// ---------------------------------------------------------------------------
// agg: ONE-PASS flash-style sparse softmax + aggregation + ELU.
// One block per node; wave w = head w. Each 16-lane (FO=64) or 8-lane (FO=32)
// sub-group keeps running (m, s, acc[4]) over its strided neighbor share:
// gather adst + row slice once per edge, online-rescale. Final shuffle-merge
// across sub-groups. No LDS, no separate e-phase.
// ---------------------------------------------------------------------------
template <int FO, bool SPLITOUT>
__global__ __launch_bounds__(256) void agg_kernel(
    const float* __restrict__ Wh,
    const float* __restrict__ asrc, const float* __restrict__ adst,
    const int* __restrict__ nbr, const int* __restrict__ deg,
    float* __restrict__ out,
    unsigned short* __restrict__ outh, unsigned short* __restrict__ outl) {
    int wslot = threadIdx.x >> 6;
    int lane = threadIdx.x & 63;
    int n = blockIdx.x;
    int h = wslot;
    int dg = deg[n];
    const int* lst = nbr + n * NBR_STRIDE;
    float my_as = asrc[(size_t)n * NHEADS + h];

    constexpr int STRIDE = NHEADS * FO;
    constexpr int LPR = FO / 4;      // lanes per neighbor row (16 or 8)
    constexpr int NPS = 64 / LPR;    // neighbors per step (4 or 8)
    int sub = lane / LPR;
    int dim4 = (lane % LPR) * 4;
    const float* whp = Wh + h * FO + dim4;

    float m = -1e30f, s = 0.f;
    f32x4 acc = {0.f, 0.f, 0.f, 0.f};

    int k = sub;
    // unroll-2: joint max per pair halves the serial exp chain
    for (; k + NPS < dg; k += 2 * NPS) {
        int cA = lst[k];
        int cB = lst[k + NPS];
        float eA = my_as + adst[(size_t)cA * NHEADS + h];
        float eB = my_as + adst[(size_t)cB * NHEADS + h];
        eA = eA >= 0.f ? eA : 0.2f * eA;
        eB = eB >= 0.f ? eB : 0.2f * eB;
        float4 vA = *reinterpret_cast<const float4*>(&whp[(size_t)cA * STRIDE]);
        float4 vB = *reinterpret_cast<const float4*>(&whp[(size_t)cB * STRIDE]);
        float mn = fmaxf(m, fmaxf(eA, eB));
        float sc = __expf(m - mn);
        float pA = __expf(eA - mn);
        float pB = __expf(eB - mn);
        s = s * sc + pA + pB;
        acc[0] = acc[0] * sc + pA * vA.x + pB * vB.x;
        acc[1] = acc[1] * sc + pA * vA.y + pB * vB.y;
        acc[2] = acc[2] * sc + pA * vA.z + pB * vB.z;
        acc[3] = acc[3] * sc + pA * vA.w + pB * vB.w;
        m = mn;
    }
    if (k < dg) {
        int c = lst[k];
        float e = my_as + adst[(size_t)c * NHEADS + h];
        e = e >= 0.f ? e : 0.2f * e;
        float4 v = *reinterpret_cast<const float4*>(&whp[(size_t)c * STRIDE]);
        float mn = fmaxf(m, e);
        float sc = __expf(m - mn);
        float p = __expf(e - mn);
        s = s * sc + p;
        acc[0] = acc[0] * sc + p * v.x;
        acc[1] = acc[1] * sc + p * v.y;
        acc[2] = acc[2] * sc + p * v.z;
        acc[3] = acc[3] * sc + p * v.w;
        m = mn;
    }
    // merge sub-groups (flash merge: rescale both sides to joint max)
    #pragma unroll
    for (int off = LPR; off < 64; off <<= 1) {
        float m2 = __shfl_xor(m, off);
        float s2 = __shfl_xor(s, off);
        float a0 = __shfl_xor(acc[0], off);
        float a1 = __shfl_xor(acc[1], off);
        float a2 = __shfl_xor(acc[2], off);
        float a3 = __shfl_xor(acc[3], off);
        float mn = fmaxf(m, m2);
        float sa = __expf(m - mn);
        float sb = __expf(m2 - mn);
        s = s * sa + s2 * sb;
        acc[0] = acc[0] * sa + a0 * sb;
        acc[1] = acc[1] * sa + a1 * sb;
        acc[2] = acc[2] * sa + a2 * sb;
        acc[3] = acc[3] * sa + a3 * sb;
        m = mn;
    }
    if (lane < LPR) {
        float inv = 1.0f / s;
        float r0 = acc[0] * inv;
        float r1 = acc[1] * inv;
        float r2 = acc[2] * inv;
        float r3 = acc[3] * inv;
        r0 = r0 > 0.f ? r0 : expm1f(r0);
        r1 = r1 > 0.f ? r1 : expm1f(r1);
        r2 = r2 > 0.f ? r2 : expm1f(r2);
        r3 = r3 > 0.f ? r3 : expm1f(r3);
        size_t idx = (size_t)n * STRIDE + h * FO + dim4;
        if constexpr (SPLITOUT) {
            ushort4 hv, lv;
            hv.x = bf16_rn(r0); lv.x = bf16_rn(r0 - bf16_f32(hv.x));
            hv.y = bf16_rn(r1); lv.y = bf16_rn(r1 - bf16_f32(hv.y));
            hv.z = bf16_rn(r2); lv.z = bf16_rn(r2 - bf16_f32(hv.z));
            hv.w = bf16_rn(r3); lv.w = bf16_rn(r3 - bf16_f32(hv.w));
            *reinterpret_cast<ushort4*>(&outh[idx]) = hv;
            *reinterpret_cast<ushort4*>(&outl[idx]) = lv;
        } else {
            *reinterpret_cast<float4*>(&out[idx]) = make_float4(r0, r1, r2, r3);
        }
    }
}

// ---------------------------------------------------------------------------
extern "C" void kernel_launch(void* const* d_in, const int* in_sizes, int n_in,
                              void* d_out, int out_size, void* d_ws, size_t ws_size,
                              hipStream_t stream) {
    const float* x   = (const float*)d_in[0];
    const float* adj = (const float*)d_in[1];
    const float* W1  = (const float*)d_in[2];
    const float* a1  = (const float*)d_in[3];
    const float* W2  = (const float*)d_in[4];
    const float* a2  = (const float*)d_in[5];
    float* outp = (float*)d_out;

    char* p = (char*)d_ws;
    auto alloc = [&](size_t bytes) -> void* {
        void* r = (void*)p;
        p += (bytes + 255) & ~(size_t)255;
        return r;
    };
    int*   nbr = (int*)alloc((size_t)NNODES * NBR_STRIDE * 4);
    int*   deg = (int*)alloc((size_t)NNODES * 4);
    unsigned short* B1h = (unsigned short*)alloc((size_t)256 * 512 * 2);
    unsigned short* B1l = (unsigned short*)alloc((size_t)256 * 512 * 2);
    unsigned short* B2h = (unsigned short*)alloc((size_t)128 * 256 * 2);
    unsigned short* B2l = (unsigned short*)alloc((size_t)128 * 256 * 2);
    float* Wh1 = (float*)alloc((size_t)NNODES * 256 * 4);
    float* as1 = (float*)alloc((size_t)NHEADS * NNODES * 4);
    float* ad1 = (float*)alloc((size_t)NHEADS * NNODES * 4);
    unsigned short* h1h = (unsigned short*)alloc((size_t)NNODES * 256 * 2);
    unsigned short* h1l = (unsigned short*)alloc((size_t)NNODES * 256 * 2);
    float* Wh2 = (float*)alloc((size_t)NNODES * 128 * 4);
    float* as2 = (float*)alloc((size_t)NHEADS * NNODES * 4);
    float* ad2 = (float*)alloc((size_t)NHEADS * NNODES * 4);

    // 1) pack W (tiny)
    pack_b_both_kernel<<<dim3((256 * 512 + 128 * 256) / 256), dim3(256), 0, stream>>>(
        W1, W2, B1h, B1l, B2h, B2l);
    // 2) fused: gemm1(+adot1, BK=32) || build_nbr
    fused1_kernel<<<dim3(512 + NNODES / 4), dim3(256), 0, stream>>>(
        adj, nbr, deg, x, B1h, B1l, a1, Wh1, as1, ad1);
    // 3) agg1 (one-pass flash) -> pre-split h1 (hi/lo bf16)
    agg_kernel<64, true><<<dim3(NNODES), dim3(256), 0, stream>>>(
        Wh1, as1, ad1, nbr, deg, nullptr, h1h, h1l);
    // 4) gemm2(+adot2), pre-split A
    gemm2_kernel<<<dim3(NNODES / 32, 2), dim3(256), 0, stream>>>(
        h1h, h1l, B2h, B2l, a2, Wh2, as2, ad2);
    // 5) agg2 (one-pass flash) -> final output
    agg_kernel<32, false><<<dim3(NNODES), dim3(256), 0, stream>>>(
        Wh2, as2, ad2, nbr, deg, outp, nullptr, nullptr);
}